// Round 8
// baseline (308.084 us; speedup 1.0000x reference)
//
#include <hip/hip_runtime.h>

typedef __attribute__((ext_vector_type(4))) float f32x4;
typedef __attribute__((ext_vector_type(16))) float f32x16;
typedef __attribute__((ext_vector_type(8))) __bf16 bf16x8;
typedef __attribute__((ext_vector_type(8))) unsigned short ushort8;
typedef __attribute__((ext_vector_type(4))) unsigned short ushort4v;
typedef __attribute__((ext_vector_type(4))) unsigned uint4v;

#define EMBED 1024
#define SEQ   2048
#define BATCH 4
#define HEADS 16
#define HDIM  64
// log2(e) / sqrt(EMBED) : combines the 1/32 scale with exp->exp2
#define SCL 0.045084220027780106f

#define GLD_LDS16(g, l) __builtin_amdgcn_global_load_lds( \
    (const __attribute__((address_space(1))) void*)(g),   \
    (__attribute__((address_space(3))) void*)(l), 16, 0, 0)
#define GLD_LDS4(g, l) __builtin_amdgcn_global_load_lds(  \
    (const __attribute__((address_space(1))) void*)(g),   \
    (__attribute__((address_space(3))) void*)(l), 4, 0, 0)

static __device__ __forceinline__ unsigned short f2bf(float f) {
  unsigned u = __builtin_bit_cast(unsigned, f);
  u += 0x7FFFu + ((u >> 16) & 1u);   // RNE
  return (unsigned short)(u >> 16);
}
// explicit-RNE packed pair (bit-identical to f2bf per element; low16 = a)
static __device__ __forceinline__ unsigned pk2bf(float a, float b) {
  unsigned ua = __builtin_bit_cast(unsigned, a);
  unsigned ub = __builtin_bit_cast(unsigned, b);
  ua += 0x7FFFu + ((ua >> 16) & 1u);
  ub += 0x7FFFu + ((ub >> 16) & 1u);
  return (ua >> 16) | (ub & 0xFFFF0000u);
}
// packed f32x2 -> bf16x2 HW op (used ONLY for P, where uniform rounding
// bias cancels in the softmax ratio; NOT for GEMM operands)
static __device__ __forceinline__ unsigned cvtpk(float a, float b) {
  unsigned r;
  asm("v_cvt_pk_bf16_f32 %0, %1, %2" : "=v"(r) : "v"(a), "v"(b));
  return r;
}

// ---- pack int32 mask -> bitmask (bit k of word w = mask[w*64+k] != 0) ----
__global__ __launch_bounds__(256) void pack_mask_kernel(
    const int* __restrict__ m, unsigned long long* __restrict__ out) {
  int t = blockIdx.x * 256 + threadIdx.x;
  unsigned long long bits = __ballot(m[t] != 0);
  if ((threadIdx.x & 63) == 0) out[t >> 6] = bits;
}

// ---- 4 weight matrices -> bf16 in one launch (dsts contiguous) ----
__global__ __launch_bounds__(256) void cvt4_kernel(
    const float* __restrict__ s0, const float* __restrict__ s1,
    const float* __restrict__ s2, const float* __restrict__ s3,
    unsigned short* __restrict__ d, int nvec) {
  int i = blockIdx.x * 256 + threadIdx.x;
  if (i >= nvec) return;
  const float* s = (blockIdx.y == 0) ? s0 : (blockIdx.y == 1) ? s1
                 : (blockIdx.y == 2) ? s2 : s3;
  unsigned short* dd = d + (size_t)blockIdx.y * nvec * 8;
  f32x4 a = ((const f32x4*)s)[2 * i];
  f32x4 b = ((const f32x4*)s)[2 * i + 1];
  ushort8 o;
#pragma unroll
  for (int j = 0; j < 4; ++j) { o[j] = f2bf(a[j]); o[4 + j] = f2bf(b[j]); }
  ((ushort8*)dd)[i] = o;
}

// ---- C[M x 1024] = A[M x 1024] @ B[1024 x 1024](bf16)^T + bias ----
// 128x128 tile, BK=32, global_load_lds, triple buffer, counted vmcnt with
// WAIT-THEN-BARRIER discipline (m201): each wave certifies its own stage-t
// writes landed (vmcnt) BEFORE the barrier that precedes any read of buf t.
// Ledger: stage = AF32?6:4 loads. Prologue: stage0+stage1, vmcnt(S), barrier
// (via loop-top). Iter t: barrier; STAGE(t+2); reads+MFMA; vmcnt(t+2<NT?S:0).
// OUT_MODE 0: bf16 row-major   1: bf16 vpT[b][h][d][s]   2: f32 row-major
template<int OUT_MODE, bool AF32>
__global__ __launch_bounds__(256, AF32 ? 2 : 3) void gemm_bt(
    const void* __restrict__ Ap, const unsigned short* __restrict__ B,
    const float* __restrict__ bias, void* __restrict__ outp) {
  __shared__ __attribute__((aligned(16))) char AbRaw[AF32 ? 3 * 16384 : 3 * 8192];
  __shared__ __attribute__((aligned(16))) unsigned short Bb[3 * 128 * 32];
  const int tid = threadIdx.x, lane = tid & 63, wv = tid >> 6;
  const int wy = wv >> 1, wx = wv & 1, ln = lane & 15, g = lane >> 4;
  const int mbase = blockIdx.x * 128, nbase = blockIdx.y * 128;

  // B staging: thread covers 16B; row = tid>>2 (+64), bytecol = (tid&3)*16
  const char* Bg = (const char*)(B + (size_t)(nbase + (tid >> 2)) * EMBED)
                   + (tid & 3) * 16;
  const size_t R64B = (size_t)64 * EMBED * 2;
  // A staging (f32): 4 rounds x 32 rows x 128B; row = r*32 + tid>>3,
  // source col inverse-swizzled so linear LDS ends up swizzled (T2 pair)
  const char* Agf = (const char*)Ap
      + ((size_t)(mbase + (tid >> 3)) * EMBED) * 4
      + (((tid & 7) * 16) ^ (((tid >> 3) & 7) << 4));
  // A staging (bf16 path): like B, linear
  const char* Agb = (const char*)Ap
      + ((size_t)(mbase + (tid >> 2)) * EMBED) * 2 + (tid & 3) * 16;

  f32x4 acc[4][4];
#pragma unroll
  for (int i = 0; i < 4; i++)
#pragma unroll
    for (int j = 0; j < 4; j++) acc[i][j] = (f32x4){0.f, 0.f, 0.f, 0.f};

  auto STAGE = [&](int buf, int kt) {
    if constexpr (AF32) {
      const char* src = Agf + (size_t)kt * 128;
      char* dst = AbRaw + buf * 16384 + tid * 16;
#pragma unroll
      for (int r = 0; r < 4; ++r)
        GLD_LDS16(src + (size_t)r * 32 * EMBED * 4, dst + r * 4096);
    } else {
      const char* src = Agb + (size_t)kt * 64;
      char* dst = AbRaw + buf * 8192 + tid * 16;
      GLD_LDS16(src, dst);
      GLD_LDS16(src + R64B, dst + 4096);
    }
    const char* bs = Bg + (size_t)kt * 64;
    char* bl = (char*)Bb + buf * 8192 + tid * 16;
    GLD_LDS16(bs, bl);
    GLD_LDS16(bs + R64B, bl + 4096);
  };

  STAGE(0, 0);
  STAGE(1, 1);
  // certify stage 0 landed (own writes) BEFORE the loop-top barrier
  if constexpr (AF32) asm volatile("s_waitcnt vmcnt(6)" ::: "memory");
  else                asm volatile("s_waitcnt vmcnt(4)" ::: "memory");
  const int NT = EMBED / 32;
  int buf = 0;
  for (int kt = 0; kt < NT; ++kt) {
    __builtin_amdgcn_s_barrier();          // everyone certified buf[kt]
    __builtin_amdgcn_sched_barrier(0);
    if (kt + 2 < NT) {
      int nb = buf + 2; if (nb >= 3) nb -= 3;
      STAGE(nb, kt + 2);
    }
    bf16x8 af[4], bfr[4];
    if constexpr (AF32) {
      const float* Af = (const float*)AbRaw + buf * 4096;
      const int aswz = (ln & 7) << 2;          // (row&7)<<4 bytes, in floats
#pragma unroll
      for (int ms = 0; ms < 4; ++ms) {
        const float* prow = Af + (wy * 64 + ms * 16 + ln) * 32;
        f32x4 l4 = *(const f32x4*)(prow + ((g * 8) ^ aswz));
        f32x4 h4 = *(const f32x4*)(prow + ((g * 8 + 4) ^ aswz));
        af[ms] = __builtin_bit_cast(bf16x8,
            (uint4v){pk2bf(l4[0], l4[1]), pk2bf(l4[2], l4[3]),
                     pk2bf(h4[0], h4[1]), pk2bf(h4[2], h4[3])});
      }
    } else {
      const unsigned short* Ab = (const unsigned short*)AbRaw + buf * 4096;
#pragma unroll
      for (int ms = 0; ms < 4; ++ms)
        af[ms] = __builtin_bit_cast(bf16x8,
            *(const ushort8*)&Ab[(wy * 64 + ms * 16 + ln) * 32 + g * 8]);
    }
#pragma unroll
    for (int ns = 0; ns < 4; ++ns)
      bfr[ns] = __builtin_bit_cast(bf16x8,
          *(const ushort8*)&Bb[buf * 4096 + (wx * 64 + ns * 16 + ln) * 32 + g * 8]);
#pragma unroll
    for (int ms = 0; ms < 4; ++ms)
#pragma unroll
      for (int ns = 0; ns < 4; ++ns)
        acc[ms][ns] = __builtin_amdgcn_mfma_f32_16x16x32_bf16(
            af[ms], bfr[ns], acc[ms][ns], 0, 0, 0);
    // certify stage kt+1 landed before next barrier; keep stage kt+2 in flight
    if (kt + 2 < NT) {
      if constexpr (AF32) asm volatile("s_waitcnt vmcnt(6)" ::: "memory");
      else                asm volatile("s_waitcnt vmcnt(4)" ::: "memory");
    } else if (kt + 1 < NT) {
      asm volatile("s_waitcnt vmcnt(0)" ::: "memory");
    }
    buf = (buf == 2) ? 0 : buf + 1;
  }

  float bv[4];
#pragma unroll
  for (int ns = 0; ns < 4; ++ns) bv[ns] = bias[nbase + wx * 64 + ns * 16 + ln];

  if (OUT_MODE == 0) {
    unsigned short* out = (unsigned short*)outp;
#pragma unroll
    for (int ms = 0; ms < 4; ++ms)
#pragma unroll
      for (int ns = 0; ns < 4; ++ns) {
        int col = nbase + wx * 64 + ns * 16 + ln;
#pragma unroll
        for (int j = 0; j < 4; ++j) {
          int row = mbase + wy * 64 + ms * 16 + g * 4 + j;
          out[(size_t)row * EMBED + col] = f2bf(acc[ms][ns][j] + bv[ns]);
        }
      }
  } else if (OUT_MODE == 1) {
    unsigned short* out = (unsigned short*)outp;
#pragma unroll
    for (int ms = 0; ms < 4; ++ms)
#pragma unroll
      for (int ns = 0; ns < 4; ++ns) {
        int row0 = mbase + wy * 64 + ms * 16 + g * 4;
        int col = nbase + wx * 64 + ns * 16 + ln;
        int b = row0 >> 11, s0 = row0 & (SEQ - 1);
        int h = col >> 6, d = col & 63;
        ushort4v pk;
#pragma unroll
        for (int j = 0; j < 4; ++j) pk[j] = f2bf(acc[ms][ns][j] + bv[ns]);
        *(ushort4v*)&out[(size_t)((b * HEADS + h) * HDIM + d) * SEQ + s0] = pk;
      }
  } else {
    float* out = (float*)outp;
#pragma unroll
    for (int ms = 0; ms < 4; ++ms)
#pragma unroll
      for (int ns = 0; ns < 4; ++ns) {
        int col = nbase + wx * 64 + ns * 16 + ln;
#pragma unroll
        for (int j = 0; j < 4; ++j) {
          int row = mbase + wy * 64 + ms * 16 + g * 4 + j;
          out[(size_t)row * EMBED + col] = acc[ms][ns][j] + bv[ns];
        }
      }
  }
}

// ---- attention: triple-buffered K/V/mask, counted vmcnt,
//      wait-then-barrier discipline; in-register P (T12) ----
__global__ __launch_bounds__(512, 4) void attn7_kernel(
    const unsigned short* __restrict__ qp, const unsigned short* __restrict__ kp,
    const unsigned short* __restrict__ vpT,
    const unsigned long long* __restrict__ mask64,
    unsigned short* __restrict__ attb) {
  __shared__ __attribute__((aligned(16))) unsigned char lds[55296];
  unsigned char* Kb = lds;               // [3][64 rows][128B] swizzled
  unsigned char* Vb = lds + 24576;       // [3][64 rows][128B] swizzled
  unsigned char* Mb = lds + 49152;       // [3][256 rows][8B]

  const int tid = threadIdx.x;
  const int lane = tid & 63, wv = tid >> 6;
  const int lo = lane & 31, hi = lane >> 5;

  // XCD-aware decode: all 8 q-chunks of one (b,h) land on one XCD
  const int flat = blockIdx.x + 8 * blockIdx.y + 128 * blockIdx.z;   // 0..511
  const int bh = (flat & 7) * 8 + ((flat >> 3) & 7);
  const int qc = flat >> 6;
  const int b = bh >> 4, h = bh & 15;
  const int qb = qc * 256 + wv * 32;
  const int q = qb + lo;

  // ---- Q fragments, pre-scaled by SCL (so p = exp2(e) directly) ----
  bf16x8 qf[4];
  {
    const unsigned short* qr = qp + (size_t)(b * SEQ + q) * EMBED + h * HDIM + hi * 8;
#pragma unroll
    for (int c = 0; c < 4; ++c) {
      ushort8 u = *(const ushort8*)(qr + 16 * c);
      bf16x8 f;
#pragma unroll
      for (int j = 0; j < 8; ++j) {
        float x = __builtin_bit_cast(float, (unsigned)u[j] << 16) * SCL;
        f[j] = (__bf16)x;
      }
      qf[c] = f;
    }
  }

  // ---- staging: 512 threads; K,V: 16B each; mask: 4B each (256 rows x 8B) ----
  const int srow = tid >> 3;                        // 0..63
  const int srcc = ((tid & 7) * 16) ^ (((tid >> 3) & 7) << 4);  // inv swizzle
  const char* kbase = (const char*)kp
      + ((size_t)(b * SEQ + srow) * EMBED + h * HDIM) * 2 + srcc;
  const char* vbase = (const char*)vpT
      + ((size_t)((b * HEADS + h) * HDIM + srow)) * SEQ * 2 + srcc;
  const char* mgbase = (const char*)mask64
      + ((size_t)(b * SEQ + qc * 256 + (tid >> 1)) * 32) * 8 + (tid & 1) * 4;

  auto STAGE = [&](int buf, int kt) {
    GLD_LDS16(kbase + (size_t)kt * 64 * EMBED * 2, Kb + buf * 8192 + tid * 16);
    GLD_LDS16(vbase + (size_t)kt * 128, Vb + buf * 8192 + tid * 16);
    GLD_LDS4(mgbase + kt * 8, Mb + buf * 2048 + tid * 4);
  };

  f32x16 oacc0, oacc1, oacc2;
#pragma unroll
  for (int i = 0; i < 16; ++i) { oacc0[i] = 0.f; oacc1[i] = 0.f; oacc2[i] = 0.f; }
  bf16x8 ones;
#pragma unroll
  for (int j = 0; j < 8; ++j) ones[j] = (__bf16)1.0f;

  const int swz = (lo & 7) << 4;

  STAGE(0, 0);
  STAGE(1, 1);
  // certify stage 0 landed (own writes) BEFORE the loop-top barrier
  asm volatile("s_waitcnt vmcnt(3)" ::: "memory");
  const int NT = SEQ / 64;
  int buf = 0;
  for (int kt = 0; kt < NT; ++kt) {
    __builtin_amdgcn_s_barrier();          // everyone certified buf[kt]
    __builtin_amdgcn_sched_barrier(0);
    if (kt + 2 < NT) {
      int nb = buf + 2; if (nb >= 3) nb -= 3;
      STAGE(nb, kt + 2);
    }
    const unsigned char* Kc = Kb + buf * 8192;
    const unsigned char* Vc = Vb + buf * 8192;
    const unsigned long long mw =
        *(const unsigned long long*)(Mb + buf * 2048 + (wv * 32 + lo) * 8);

    // ---- QK^T (swapped: A=K, B=Q -> D[k][q]) + in-register P build ----
    bf16x8 PA[4];
#pragma unroll
    for (int kg = 0; kg < 2; ++kg) {
      f32x16 e;
#pragma unroll
      for (int i = 0; i < 16; ++i) e[i] = 0.f;
      const int krow = kg * 32 + lo;
#pragma unroll
      for (int c = 0; c < 4; ++c) {
        const int colb = (16 * c + 8 * hi) * 2;
        bf16x8 kf = *(const bf16x8*)(Kc + krow * 128 + (colb ^ swz));
        e = __builtin_amdgcn_mfma_f32_32x32x16_bf16(kf, qf[c], e, 0, 0, 0);
      }
      // mask + exp: p[4m+j] is k_local = 8m + 4hi + j; bit (8m+j) of mh
      const unsigned mh = (unsigned)(mw >> (kg * 32 + 4 * hi));
      float p[16];
#pragma unroll
      for (int m = 0; m < 4; ++m)
#pragma unroll
        for (int j = 0; j < 4; ++j) {
          float pe = __builtin_amdgcn_exp2f(e[4 * m + j]);
          p[4 * m + j] = (mh & (1u << (8 * m + j))) ? pe : 0.f;
        }
      // pack pairs to bf16; swap lane-halves: one permlane fills 2 words
      unsigned wA0 = cvtpk(p[0], p[1]),   wB0 = cvtpk(p[2], p[3]);
      unsigned wA1 = cvtpk(p[4], p[5]),   wB1 = cvtpk(p[6], p[7]);
      unsigned wA2 = cvtpk(p[8], p[9]),   wB2 = cvtpk(p[10], p[11]);
      unsigned wA3 = cvtpk(p[12], p[13]), wB3 = cvtpk(p[14], p[15]);
      asm("v_permlane32_swap_b32 %0, %1" : "+v"(wA0), "+v"(wA1));
      asm("v_permlane32_swap_b32 %0, %1" : "+v"(wB0), "+v"(wB1));
      asm("v_permlane32_swap_b32 %0, %1" : "+v"(wA2), "+v"(wA3));
      asm("v_permlane32_swap_b32 %0, %1" : "+v"(wB2), "+v"(wB3));
      PA[2 * kg]     = __builtin_bit_cast(bf16x8, (uint4v){wA0, wB0, wA1, wB1});
      PA[2 * kg + 1] = __builtin_bit_cast(bf16x8, (uint4v){wA2, wB2, wA3, wB3});
    }

    // ---- PV: A=P (in reg), B=V^T rows (d) -> D[q][d]; +ones denom ----
    __builtin_amdgcn_s_setprio(1);
#pragma unroll
    for (int c = 0; c < 4; ++c) {
      const int pcolb = 32 * c + 16 * hi;
      bf16x8 pf = PA[c];
      {
        bf16x8 vf = *(const bf16x8*)(Vc + lo * 128 + (pcolb ^ swz));
        oacc0 = __builtin_amdgcn_mfma_f32_32x32x16_bf16(pf, vf, oacc0, 0, 0, 0);
      }
      {
        const int drow = 32 + lo;
        bf16x8 vf = *(const bf16x8*)(Vc + drow * 128 + (pcolb ^ swz));
        oacc1 = __builtin_amdgcn_mfma_f32_32x32x16_bf16(pf, vf, oacc1, 0, 0, 0);
      }
      oacc2 = __builtin_amdgcn_mfma_f32_32x32x16_bf16(pf, ones, oacc2, 0, 0, 0);
    }
    __builtin_amdgcn_s_setprio(0);
    // certify stage kt+1 landed before next barrier; keep stage kt+2 in flight
    if (kt + 2 < NT) {
      asm volatile("s_waitcnt vmcnt(3)" ::: "memory");
    } else if (kt + 1 < NT) {
      asm volatile("s_waitcnt vmcnt(0)" ::: "memory");
    }
    buf = (buf == 2) ? 0 : buf + 1;
  }

  // ---- oacc2[r] = sum_k P[q_r][k] (same lane layout as oacc0) ----
#pragma unroll
  for (int r = 0; r < 16; ++r) {
    const int qq = qb + (r & 3) + 8 * (r >> 2) + 4 * hi;
    const float dinv = 1.0f / oacc2[r];
    unsigned short* orow = attb + (size_t)(b * SEQ + qq) * EMBED + h * HDIM;
    orow[lo] = f2bf(oacc0[r] * dinv);
    orow[32 + lo] = f2bf(oacc1[r] * dinv);
  }
}

extern "C" void kernel_launch(void* const* d_in, const int* in_sizes, int n_in,
                              void* d_out, int out_size, void* d_ws, size_t ws_size,
                              hipStream_t stream) {
  const float* q    = (const float*)d_in[0];
  const float* k    = (const float*)d_in[1];
  const float* v    = (const float*)d_in[2];
  const int*   mask = (const int*)d_in[3];
  const float* wq_w = (const float*)d_in[4];
  const float* wq_b = (const float*)d_in[5];
  const float* wk_w = (const float*)d_in[6];
  const float* wk_b = (const float*)d_in[7];
  const float* wv_w = (const float*)d_in[8];
  const float* wv_b = (const float*)d_in[9];
  const float* fo_w = (const float*)d_in[10];
  const float* fo_b = (const float*)d_in[11];

  char* ws = (char*)d_ws;
  const size_t MB = 1024 * 1024;
  unsigned short* stage = (unsigned short*)(ws);            // 16 MB (attn out bf16)
  unsigned short* wqb   = (unsigned short*)(ws + 16 * MB);  // 2 MB each, contiguous
  unsigned short* qp    = (unsigned short*)(ws + 24 * MB);  // 16 MB
  unsigned short* kp    = (unsigned short*)(ws + 40 * MB);  // 16 MB
  unsigned short* vpT   = (unsigned short*)(ws + 56 * MB);  // 16 MB
  unsigned long long* m64 = (unsigned long long*)(ws + 72 * MB);  // 2 MB

  const int NVW = EMBED * EMBED / 8;         // 131072 vec8

  // 1. pack mask bits (67MB -> 2MB, L3-resident for all 16 heads)
  pack_mask_kernel<<<(BATCH * SEQ * SEQ) / 256, 256, 0, stream>>>(mask, m64);

  // 2. weights -> bf16 (one launch; dsts contiguous at ws+16MB)
  cvt4_kernel<<<dim3(NVW / 256, 4), 256, 0, stream>>>(wq_w, wk_w, wv_w, fo_w, wqb, NVW);
  unsigned short* wkb = wqb + (size_t)NVW * 8;
  unsigned short* wvb = wkb + (size_t)NVW * 8;
  unsigned short* fob = wvb + (size_t)NVW * 8;

  // 3-5. projections: read f32 inputs directly, RNE-convert in-kernel
  dim3 gg((BATCH * SEQ) / 128, EMBED / 128);
  gemm_bt<0, true><<<gg, 256, 0, stream>>>(q, wqb, wq_b, qp);
  gemm_bt<0, true><<<gg, 256, 0, stream>>>(k, wkb, wk_b, kp);
  gemm_bt<1, true><<<gg, 256, 0, stream>>>(v, wvb, wv_b, vpT);

  // 6. fused masked attention -> bf16 into `stage`
  attn7_kernel<<<dim3(8, HEADS, BATCH), 512, 0, stream>>>(qp, kp, vpT, m64, stage);

  // 7. output projection -> d_out (f32)
  gemm_bt<2, false><<<gg, 256, 0, stream>>>(stage, fob, fo_b, (float*)d_out);
}

// Round 10
// 260.698 us; speedup vs baseline: 1.1818x; 1.1818x over previous
//
#include <hip/hip_runtime.h>

typedef __attribute__((ext_vector_type(4))) float f32x4;
typedef __attribute__((ext_vector_type(16))) float f32x16;
typedef __attribute__((ext_vector_type(8))) __bf16 bf16x8;
typedef __attribute__((ext_vector_type(8))) unsigned short ushort8;
typedef __attribute__((ext_vector_type(4))) unsigned short ushort4v;
typedef __attribute__((ext_vector_type(4))) unsigned uint4v;

#define EMBED 1024
#define SEQ   2048
#define BATCH 4
#define HEADS 16
#define HDIM  64
// log2(e) / sqrt(EMBED) : combines the 1/32 scale with exp->exp2
#define SCL 0.045084220027780106f

#define GLD_LDS16(g, l) __builtin_amdgcn_global_load_lds( \
    (const __attribute__((address_space(1))) void*)(g),   \
    (__attribute__((address_space(3))) void*)(l), 16, 0, 0)
#define GLD_LDS4(g, l) __builtin_amdgcn_global_load_lds(  \
    (const __attribute__((address_space(1))) void*)(g),   \
    (__attribute__((address_space(3))) void*)(l), 4, 0, 0)

static __device__ __forceinline__ unsigned short f2bf(float f) {
  unsigned u = __builtin_bit_cast(unsigned, f);
  u += 0x7FFFu + ((u >> 16) & 1u);   // RNE
  return (unsigned short)(u >> 16);
}
// packed f32x2 -> bf16x2 HW op (used ONLY for P, where uniform rounding
// bias cancels in the softmax ratio; NOT for GEMM operands)
static __device__ __forceinline__ unsigned cvtpk(float a, float b) {
  unsigned r;
  asm("v_cvt_pk_bf16_f32 %0, %1, %2" : "=v"(r) : "v"(a), "v"(b));
  return r;
}

// ---- pack int32 mask -> bitmask (bit k of word w = mask[w*64+k] != 0) ----
__global__ __launch_bounds__(256) void pack_mask_kernel(
    const int* __restrict__ m, unsigned long long* __restrict__ out) {
  int t = blockIdx.x * 256 + threadIdx.x;
  unsigned long long bits = __ballot(m[t] != 0);
  if ((threadIdx.x & 63) == 0) out[t >> 6] = bits;
}

// ---- f32 -> bf16 vectorized convert (8 elems/thread) ----
__global__ __launch_bounds__(256) void cvt_kernel(
    const float* __restrict__ s, unsigned short* __restrict__ d, int nvec) {
  int i = blockIdx.x * 256 + threadIdx.x;
  if (i >= nvec) return;
  f32x4 a = ((const f32x4*)s)[2 * i];
  f32x4 b = ((const f32x4*)s)[2 * i + 1];
  ushort8 o;
#pragma unroll
  for (int j = 0; j < 4; ++j) { o[j] = f2bf(a[j]); o[4 + j] = f2bf(b[j]); }
  ((ushort8*)d)[i] = o;
}

// ---- 4 weight matrices -> bf16 in one launch (dsts contiguous) ----
__global__ __launch_bounds__(256) void cvt4_kernel(
    const float* __restrict__ s0, const float* __restrict__ s1,
    const float* __restrict__ s2, const float* __restrict__ s3,
    unsigned short* __restrict__ d, int nvec) {
  int i = blockIdx.x * 256 + threadIdx.x;
  if (i >= nvec) return;
  const float* s = (blockIdx.y == 0) ? s0 : (blockIdx.y == 1) ? s1
                 : (blockIdx.y == 2) ? s2 : s3;
  unsigned short* dd = d + (size_t)blockIdx.y * nvec * 8;
  f32x4 a = ((const f32x4*)s)[2 * i];
  f32x4 b = ((const f32x4*)s)[2 * i + 1];
  ushort8 o;
#pragma unroll
  for (int j = 0; j < 4; ++j) { o[j] = f2bf(a[j]); o[4 + j] = f2bf(b[j]); }
  ((ushort8*)dd)[i] = o;
}

// ---- C[M x 1024] = A[M x 1024](bf16) @ B[1024 x 1024](bf16)^T + bias ----
// 128x128 tile, BK=32, global_load_lds w16, triple buffer, counted vmcnt,
// WAIT-THEN-BARRIER discipline (race-free, verified round 8).
// Ledger: stage = 4 loads; prologue stage0+stage1, vmcnt(4); iter t:
// barrier; STAGE(t+2); reads+MFMA; vmcnt(t+2<NT ? 4 : 0).
// OUT_MODE 0: bf16 row-major   1: bf16 vpT[b][h][d][s]   2: f32 row-major
template<int OUT_MODE>
__global__ __launch_bounds__(256, 3) void gemm_bt(
    const unsigned short* __restrict__ A, const unsigned short* __restrict__ B,
    const float* __restrict__ bias, void* __restrict__ outp) {
  __shared__ __attribute__((aligned(16))) unsigned short Ab[3 * 128 * 32];
  __shared__ __attribute__((aligned(16))) unsigned short Bb[3 * 128 * 32];
  const int tid = threadIdx.x, lane = tid & 63, wv = tid >> 6;
  const int wy = wv >> 1, wx = wv & 1, ln = lane & 15, g = lane >> 4;
  const int mbase = blockIdx.x * 128, nbase = blockIdx.y * 128;

  // staging: thread covers 16B; row = tid>>2 (+64 round 1), bytecol=(tid&3)*16
  const char* Ag = (const char*)(A + (size_t)(mbase + (tid >> 2)) * EMBED)
                   + (tid & 3) * 16;
  const char* Bg = (const char*)(B + (size_t)(nbase + (tid >> 2)) * EMBED)
                   + (tid & 3) * 16;
  const size_t R64B = (size_t)64 * EMBED * 2;

  f32x4 acc[4][4];
#pragma unroll
  for (int i = 0; i < 4; i++)
#pragma unroll
    for (int j = 0; j < 4; j++) acc[i][j] = (f32x4){0.f, 0.f, 0.f, 0.f};

  auto STAGE = [&](int buf, int kt) {
    const size_t koff = (size_t)kt * 64;   // BK=32 bf16 = 64 bytes
    char* al = (char*)Ab + buf * 8192 + tid * 16;
    char* bl = (char*)Bb + buf * 8192 + tid * 16;
    GLD_LDS16(Ag + koff, al);
    GLD_LDS16(Ag + koff + R64B, al + 4096);
    GLD_LDS16(Bg + koff, bl);
    GLD_LDS16(Bg + koff + R64B, bl + 4096);
  };

  STAGE(0, 0);
  STAGE(1, 1);
  asm volatile("s_waitcnt vmcnt(4)" ::: "memory");   // certify stage 0
  const int NT = EMBED / 32;
  int buf = 0;
  for (int kt = 0; kt < NT; ++kt) {
    __builtin_amdgcn_s_barrier();          // everyone certified buf[kt]
    __builtin_amdgcn_sched_barrier(0);
    if (kt + 2 < NT) {
      int nb = buf + 2; if (nb >= 3) nb -= 3;
      STAGE(nb, kt + 2);
    }
    bf16x8 af[4], bfr[4];
#pragma unroll
    for (int ms = 0; ms < 4; ++ms)
      af[ms] = __builtin_bit_cast(bf16x8,
          *(const ushort8*)&Ab[buf * 4096 + (wy * 64 + ms * 16 + ln) * 32 + g * 8]);
#pragma unroll
    for (int ns = 0; ns < 4; ++ns)
      bfr[ns] = __builtin_bit_cast(bf16x8,
          *(const ushort8*)&Bb[buf * 4096 + (wx * 64 + ns * 16 + ln) * 32 + g * 8]);
#pragma unroll
    for (int ms = 0; ms < 4; ++ms)
#pragma unroll
      for (int ns = 0; ns < 4; ++ns)
        acc[ms][ns] = __builtin_amdgcn_mfma_f32_16x16x32_bf16(
            af[ms], bfr[ns], acc[ms][ns], 0, 0, 0);
    // certify stage kt+1 before next barrier; keep stage kt+2 in flight
    if (kt + 2 < NT) {
      asm volatile("s_waitcnt vmcnt(4)" ::: "memory");
    } else if (kt + 1 < NT) {
      asm volatile("s_waitcnt vmcnt(0)" ::: "memory");
    }
    buf = (buf == 2) ? 0 : buf + 1;
  }

  float bv[4];
#pragma unroll
  for (int ns = 0; ns < 4; ++ns) bv[ns] = bias[nbase + wx * 64 + ns * 16 + ln];

  if (OUT_MODE == 0) {
    unsigned short* out = (unsigned short*)outp;
#pragma unroll
    for (int ms = 0; ms < 4; ++ms)
#pragma unroll
      for (int ns = 0; ns < 4; ++ns) {
        int col = nbase + wx * 64 + ns * 16 + ln;
#pragma unroll
        for (int j = 0; j < 4; ++j) {
          int row = mbase + wy * 64 + ms * 16 + g * 4 + j;
          out[(size_t)row * EMBED + col] = f2bf(acc[ms][ns][j] + bv[ns]);
        }
      }
  } else if (OUT_MODE == 1) {
    unsigned short* out = (unsigned short*)outp;
#pragma unroll
    for (int ms = 0; ms < 4; ++ms)
#pragma unroll
      for (int ns = 0; ns < 4; ++ns) {
        int row0 = mbase + wy * 64 + ms * 16 + g * 4;
        int col = nbase + wx * 64 + ns * 16 + ln;
        int b = row0 >> 11, s0 = row0 & (SEQ - 1);
        int h = col >> 6, d = col & 63;
        ushort4v pk;
#pragma unroll
        for (int j = 0; j < 4; ++j) pk[j] = f2bf(acc[ms][ns][j] + bv[ns]);
        *(ushort4v*)&out[(size_t)((b * HEADS + h) * HDIM + d) * SEQ + s0] = pk;
      }
  } else {
    float* out = (float*)outp;
#pragma unroll
    for (int ms = 0; ms < 4; ++ms)
#pragma unroll
      for (int ns = 0; ns < 4; ++ns) {
        int col = nbase + wx * 64 + ns * 16 + ln;
#pragma unroll
        for (int j = 0; j < 4; ++j) {
          int row = mbase + wy * 64 + ms * 16 + g * 4 + j;
          out[(size_t)row * EMBED + col] = acc[ms][ns][j] + bv[ns];
        }
      }
  }
}

// ---- attention (round-8 verbatim): triple-buffered K/V/mask, counted
//      vmcnt, wait-then-barrier; in-register P (T12); select masking ----
__global__ __launch_bounds__(512, 4) void attn7_kernel(
    const unsigned short* __restrict__ qp, const unsigned short* __restrict__ kp,
    const unsigned short* __restrict__ vpT,
    const unsigned long long* __restrict__ mask64,
    unsigned short* __restrict__ attb) {
  __shared__ __attribute__((aligned(16))) unsigned char lds[55296];
  unsigned char* Kb = lds;               // [3][64 rows][128B] swizzled
  unsigned char* Vb = lds + 24576;       // [3][64 rows][128B] swizzled
  unsigned char* Mb = lds + 49152;       // [3][256 rows][8B]

  const int tid = threadIdx.x;
  const int lane = tid & 63, wv = tid >> 6;
  const int lo = lane & 31, hi = lane >> 5;

  // XCD-aware decode: all 8 q-chunks of one (b,h) land on one XCD
  const int flat = blockIdx.x + 8 * blockIdx.y + 128 * blockIdx.z;   // 0..511
  const int bh = (flat & 7) * 8 + ((flat >> 3) & 7);
  const int qc = flat >> 6;
  const int b = bh >> 4, h = bh & 15;
  const int qb = qc * 256 + wv * 32;
  const int q = qb + lo;

  // ---- Q fragments, pre-scaled by SCL (so p = exp2(e) directly) ----
  bf16x8 qf[4];
  {
    const unsigned short* qr = qp + (size_t)(b * SEQ + q) * EMBED + h * HDIM + hi * 8;
#pragma unroll
    for (int c = 0; c < 4; ++c) {
      ushort8 u = *(const ushort8*)(qr + 16 * c);
      bf16x8 f;
#pragma unroll
      for (int j = 0; j < 8; ++j) {
        float x = __builtin_bit_cast(float, (unsigned)u[j] << 16) * SCL;
        f[j] = (__bf16)x;
      }
      qf[c] = f;
    }
  }

  // ---- staging: 512 threads; K,V: 16B each; mask: 4B each (256 rows x 8B) ----
  const int srow = tid >> 3;                        // 0..63
  const int srcc = ((tid & 7) * 16) ^ (((tid >> 3) & 7) << 4);  // inv swizzle
  const char* kbase = (const char*)kp
      + ((size_t)(b * SEQ + srow) * EMBED + h * HDIM) * 2 + srcc;
  const char* vbase = (const char*)vpT
      + ((size_t)((b * HEADS + h) * HDIM + srow)) * SEQ * 2 + srcc;
  const char* mgbase = (const char*)mask64
      + ((size_t)(b * SEQ + qc * 256 + (tid >> 1)) * 32) * 8 + (tid & 1) * 4;

  auto STAGE = [&](int buf, int kt) {
    GLD_LDS16(kbase + (size_t)kt * 64 * EMBED * 2, Kb + buf * 8192 + tid * 16);
    GLD_LDS16(vbase + (size_t)kt * 128, Vb + buf * 8192 + tid * 16);
    GLD_LDS4(mgbase + kt * 8, Mb + buf * 2048 + tid * 4);
  };

  f32x16 oacc0, oacc1, oacc2;
#pragma unroll
  for (int i = 0; i < 16; ++i) { oacc0[i] = 0.f; oacc1[i] = 0.f; oacc2[i] = 0.f; }
  bf16x8 ones;
#pragma unroll
  for (int j = 0; j < 8; ++j) ones[j] = (__bf16)1.0f;

  const int swz = (lo & 7) << 4;

  STAGE(0, 0);
  STAGE(1, 1);
  asm volatile("s_waitcnt vmcnt(3)" ::: "memory");   // certify stage 0
  const int NT = SEQ / 64;
  int buf = 0;
  for (int kt = 0; kt < NT; ++kt) {
    __builtin_amdgcn_s_barrier();          // everyone certified buf[kt]
    __builtin_amdgcn_sched_barrier(0);
    if (kt + 2 < NT) {
      int nb = buf + 2; if (nb >= 3) nb -= 3;
      STAGE(nb, kt + 2);
    }
    const unsigned char* Kc = Kb + buf * 8192;
    const unsigned char* Vc = Vb + buf * 8192;
    const unsigned long long mw =
        *(const unsigned long long*)(Mb + buf * 2048 + (wv * 32 + lo) * 8);

    // ---- QK^T (swapped: A=K, B=Q -> D[k][q]) + in-register P build ----
    bf16x8 PA[4];
#pragma unroll
    for (int kg = 0; kg < 2; ++kg) {
      f32x16 e;
#pragma unroll
      for (int i = 0; i < 16; ++i) e[i] = 0.f;
      const int krow = kg * 32 + lo;
#pragma unroll
      for (int c = 0; c < 4; ++c) {
        const int colb = (16 * c + 8 * hi) * 2;
        bf16x8 kf = *(const bf16x8*)(Kc + krow * 128 + (colb ^ swz));
        e = __builtin_amdgcn_mfma_f32_32x32x16_bf16(kf, qf[c], e, 0, 0, 0);
      }
      // mask + exp: p[4m+j] is k_local = 8m + 4hi + j; bit (8m+j) of mh
      const unsigned mh = (unsigned)(mw >> (kg * 32 + 4 * hi));
      float p[16];
#pragma unroll
      for (int m = 0; m < 4; ++m)
#pragma unroll
        for (int j = 0; j < 4; ++j) {
          float pe = __builtin_amdgcn_exp2f(e[4 * m + j]);
          p[4 * m + j] = (mh & (1u << (8 * m + j))) ? pe : 0.f;
        }
      // pack pairs to bf16; swap lane-halves: one permlane fills 2 words
      unsigned wA0 = cvtpk(p[0], p[1]),   wB0 = cvtpk(p[2], p[3]);
      unsigned wA1 = cvtpk(p[4], p[5]),   wB1 = cvtpk(p[6], p[7]);
      unsigned wA2 = cvtpk(p[8], p[9]),   wB2 = cvtpk(p[10], p[11]);
      unsigned wA3 = cvtpk(p[12], p[13]), wB3 = cvtpk(p[14], p[15]);
      asm("v_permlane32_swap_b32 %0, %1" : "+v"(wA0), "+v"(wA1));
      asm("v_permlane32_swap_b32 %0, %1" : "+v"(wB0), "+v"(wB1));
      asm("v_permlane32_swap_b32 %0, %1" : "+v"(wA2), "+v"(wA3));
      asm("v_permlane32_swap_b32 %0, %1" : "+v"(wB2), "+v"(wB3));
      PA[2 * kg]     = __builtin_bit_cast(bf16x8, (uint4v){wA0, wB0, wA1, wB1});
      PA[2 * kg + 1] = __builtin_bit_cast(bf16x8, (uint4v){wA2, wB2, wA3, wB3});
    }

    // ---- PV: A=P (in reg), B=V^T rows (d) -> D[q][d]; +ones denom ----
    __builtin_amdgcn_s_setprio(1);
#pragma unroll
    for (int c = 0; c < 4; ++c) {
      const int pcolb = 32 * c + 16 * hi;
      bf16x8 pf = PA[c];
      {
        bf16x8 vf = *(const bf16x8*)(Vc + lo * 128 + (pcolb ^ swz));
        oacc0 = __builtin_amdgcn_mfma_f32_32x32x16_bf16(pf, vf, oacc0, 0, 0, 0);
      }
      {
        const int drow = 32 + lo;
        bf16x8 vf = *(const bf16x8*)(Vc + drow * 128 + (pcolb ^ swz));
        oacc1 = __builtin_amdgcn_mfma_f32_32x32x16_bf16(pf, vf, oacc1, 0, 0, 0);
      }
      oacc2 = __builtin_amdgcn_mfma_f32_32x32x16_bf16(pf, ones, oacc2, 0, 0, 0);
    }
    __builtin_amdgcn_s_setprio(0);
    // certify stage kt+1 before next barrier; keep stage kt+2 in flight
    if (kt + 2 < NT) {
      asm volatile("s_waitcnt vmcnt(3)" ::: "memory");
    } else if (kt + 1 < NT) {
      asm volatile("s_waitcnt vmcnt(0)" ::: "memory");
    }
    buf = (buf == 2) ? 0 : buf + 1;
  }

  // ---- oacc2[r] = sum_k P[q_r][k] (same lane layout as oacc0) ----
#pragma unroll
  for (int r = 0; r < 16; ++r) {
    const int qq = qb + (r & 3) + 8 * (r >> 2) + 4 * hi;
    const float dinv = 1.0f / oacc2[r];
    unsigned short* orow = attb + (size_t)(b * SEQ + qq) * EMBED + h * HDIM;
    orow[lo] = f2bf(oacc0[r] * dinv);
    orow[32 + lo] = f2bf(oacc1[r] * dinv);
  }
}

extern "C" void kernel_launch(void* const* d_in, const int* in_sizes, int n_in,
                              void* d_out, int out_size, void* d_ws, size_t ws_size,
                              hipStream_t stream) {
  const float* q    = (const float*)d_in[0];
  const float* k    = (const float*)d_in[1];
  const float* v    = (const float*)d_in[2];
  const int*   mask = (const int*)d_in[3];
  const float* wq_w = (const float*)d_in[4];
  const float* wq_b = (const float*)d_in[5];
  const float* wk_w = (const float*)d_in[6];
  const float* wk_b = (const float*)d_in[7];
  const float* wv_w = (const float*)d_in[8];
  const float* wv_b = (const float*)d_in[9];
  const float* fo_w = (const float*)d_in[10];
  const float* fo_b = (const float*)d_in[11];

  char* ws = (char*)d_ws;
  const size_t MB = 1024 * 1024;
  unsigned short* stage = (unsigned short*)(ws);            // 16 MB (X bf16 / attn out)
  unsigned short* wqb   = (unsigned short*)(ws + 16 * MB);  // 2 MB each, contiguous
  unsigned short* qp    = (unsigned short*)(ws + 24 * MB);  // 16 MB
  unsigned short* kp    = (unsigned short*)(ws + 40 * MB);  // 16 MB
  unsigned short* vpT   = (unsigned short*)(ws + 56 * MB);  // 16 MB
  unsigned long long* m64 = (unsigned long long*)(ws + 72 * MB);  // 2 MB

  const int NVX = BATCH * SEQ * EMBED / 8;   // 1048576 vec8
  const int NVW = EMBED * EMBED / 8;         // 131072 vec8

  // 1. pack mask bits (67MB -> 2MB, L3-resident for all 16 heads)
  pack_mask_kernel<<<(BATCH * SEQ * SEQ) / 256, 256, 0, stream>>>(mask, m64);

  // 2. weights -> bf16 (one launch; dsts contiguous at ws+16MB)
  cvt4_kernel<<<dim3(NVW / 256, 4), 256, 0, stream>>>(wq_w, wk_w, wv_w, fo_w, wqb, NVW);
  unsigned short* wkb = wqb + (size_t)NVW * 8;
  unsigned short* wvb = wkb + (size_t)NVW * 8;
  unsigned short* fob = wvb + (size_t)NVW * 8;

  // 3-5. projections (X staged through `stage` as bf16)
  dim3 gg((BATCH * SEQ) / 128, EMBED / 128);
  cvt_kernel<<<NVX / 256, 256, 0, stream>>>(q, stage, NVX);
  gemm_bt<0><<<gg, 256, 0, stream>>>(stage, wqb, wq_b, qp);
  cvt_kernel<<<NVX / 256, 256, 0, stream>>>(k, stage, NVX);
  gemm_bt<0><<<gg, 256, 0, stream>>>(stage, wkb, wk_b, kp);
  cvt_kernel<<<NVX / 256, 256, 0, stream>>>(v, stage, NVX);
  gemm_bt<1><<<gg, 256, 0, stream>>>(stage, wvb, wv_b, vpT);

  // 6. fused masked attention -> bf16 into `stage`
  attn7_kernel<<<dim3(8, HEADS, BATCH), 512, 0, stream>>>(qp, kp, vpT, m64, stage);

  // 7. output projection -> d_out (f32)
  gemm_bt<2><<<gg, 256, 0, stream>>>(stage, fob, fo_b, (float*)d_out);
}

// Round 11
// 258.212 us; speedup vs baseline: 1.1931x; 1.0096x over previous
//
#include <hip/hip_runtime.h>

typedef __attribute__((ext_vector_type(4))) float f32x4;
typedef __attribute__((ext_vector_type(16))) float f32x16;
typedef __attribute__((ext_vector_type(8))) __bf16 bf16x8;
typedef __attribute__((ext_vector_type(8))) unsigned short ushort8;
typedef __attribute__((ext_vector_type(4))) unsigned short ushort4v;
typedef __attribute__((ext_vector_type(4))) unsigned uint4v;

#define EMBED 1024
#define SEQ   2048
#define BATCH 4
#define HEADS 16
#define HDIM  64
// log2(e) / sqrt(EMBED) : combines the 1/32 scale with exp->exp2
#define SCL 0.045084220027780106f

#define GLD_LDS16(g, l) __builtin_amdgcn_global_load_lds( \
    (const __attribute__((address_space(1))) void*)(g),   \
    (__attribute__((address_space(3))) void*)(l), 16, 0, 0)
#define GLD_LDS4(g, l) __builtin_amdgcn_global_load_lds(  \
    (const __attribute__((address_space(1))) void*)(g),   \
    (__attribute__((address_space(3))) void*)(l), 4, 0, 0)

static __device__ __forceinline__ unsigned short f2bf(float f) {
  unsigned u = __builtin_bit_cast(unsigned, f);
  u += 0x7FFFu + ((u >> 16) & 1u);   // RNE
  return (unsigned short)(u >> 16);
}
// packed f32x2 -> bf16x2 HW op (used ONLY for P, where uniform rounding
// bias cancels in the softmax ratio; NOT for GEMM operands)
static __device__ __forceinline__ unsigned cvtpk(float a, float b) {
  unsigned r;
  asm("v_cvt_pk_bf16_f32 %0, %1, %2" : "=v"(r) : "v"(a), "v"(b));
  return r;
}

// ---- pack int32 mask -> bitmask (bit k of word w = mask[w*64+k] != 0) ----
__global__ __launch_bounds__(256) void pack_mask_kernel(
    const int* __restrict__ m, unsigned long long* __restrict__ out) {
  int t = blockIdx.x * 256 + threadIdx.x;
  unsigned long long bits = __ballot(m[t] != 0);
  if ((threadIdx.x & 63) == 0) out[t >> 6] = bits;
}

// ---- q,k,v -> bf16 in one launch (blockIdx.y selects tensor) ----
__global__ __launch_bounds__(256) void cvt3_kernel(
    const float* __restrict__ s0, const float* __restrict__ s1,
    const float* __restrict__ s2,
    unsigned short* __restrict__ d0, unsigned short* __restrict__ d1,
    unsigned short* __restrict__ d2, int nvec) {
  int i = blockIdx.x * 256 + threadIdx.x;
  if (i >= nvec) return;
  const float* s = (blockIdx.y == 0) ? s0 : (blockIdx.y == 1) ? s1 : s2;
  unsigned short* d = (blockIdx.y == 0) ? d0 : (blockIdx.y == 1) ? d1 : d2;
  f32x4 a = ((const f32x4*)s)[2 * i];
  f32x4 b = ((const f32x4*)s)[2 * i + 1];
  ushort8 o;
#pragma unroll
  for (int j = 0; j < 4; ++j) { o[j] = f2bf(a[j]); o[4 + j] = f2bf(b[j]); }
  ((ushort8*)d)[i] = o;
}

// ---- 4 weight matrices -> bf16 in one launch (dsts contiguous) ----
__global__ __launch_bounds__(256) void cvt4_kernel(
    const float* __restrict__ s0, const float* __restrict__ s1,
    const float* __restrict__ s2, const float* __restrict__ s3,
    unsigned short* __restrict__ d, int nvec) {
  int i = blockIdx.x * 256 + threadIdx.x;
  if (i >= nvec) return;
  const float* s = (blockIdx.y == 0) ? s0 : (blockIdx.y == 1) ? s1
                 : (blockIdx.y == 2) ? s2 : s3;
  unsigned short* dd = d + (size_t)blockIdx.y * nvec * 8;
  f32x4 a = ((const f32x4*)s)[2 * i];
  f32x4 b = ((const f32x4*)s)[2 * i + 1];
  ushort8 o;
#pragma unroll
  for (int j = 0; j < 4; ++j) { o[j] = f2bf(a[j]); o[4 + j] = f2bf(b[j]); }
  ((ushort8*)dd)[i] = o;
}

// ---- C[M x 1024] = A[M x 1024](bf16) @ B[1024 x 1024](bf16)^T + bias ----
// 128x128 tile, BK=32, global_load_lds w16, triple buffer, counted vmcnt,
// WAIT-THEN-BARRIER discipline (race-free, verified rounds 8/10).
// OUT_MODE 0: bf16 row-major   1: bf16 vpT[b][h][d][s]   2: f32 row-major
template<int OUT_MODE>
__global__ __launch_bounds__(256, 3) void gemm_bt(
    const unsigned short* __restrict__ A, const unsigned short* __restrict__ B,
    const float* __restrict__ bias, void* __restrict__ outp) {
  __shared__ __attribute__((aligned(16))) unsigned short Ab[3 * 128 * 32];
  __shared__ __attribute__((aligned(16))) unsigned short Bb[3 * 128 * 32];
  const int tid = threadIdx.x, lane = tid & 63, wv = tid >> 6;
  const int wy = wv >> 1, wx = wv & 1, ln = lane & 15, g = lane >> 4;
  const int mbase = blockIdx.x * 128, nbase = blockIdx.y * 128;

  const char* Ag = (const char*)(A + (size_t)(mbase + (tid >> 2)) * EMBED)
                   + (tid & 3) * 16;
  const char* Bg = (const char*)(B + (size_t)(nbase + (tid >> 2)) * EMBED)
                   + (tid & 3) * 16;
  const size_t R64B = (size_t)64 * EMBED * 2;

  f32x4 acc[4][4];
#pragma unroll
  for (int i = 0; i < 4; i++)
#pragma unroll
    for (int j = 0; j < 4; j++) acc[i][j] = (f32x4){0.f, 0.f, 0.f, 0.f};

  auto STAGE = [&](int buf, int kt) {
    const size_t koff = (size_t)kt * 64;   // BK=32 bf16 = 64 bytes
    char* al = (char*)Ab + buf * 8192 + tid * 16;
    char* bl = (char*)Bb + buf * 8192 + tid * 16;
    GLD_LDS16(Ag + koff, al);
    GLD_LDS16(Ag + koff + R64B, al + 4096);
    GLD_LDS16(Bg + koff, bl);
    GLD_LDS16(Bg + koff + R64B, bl + 4096);
  };

  STAGE(0, 0);
  STAGE(1, 1);
  asm volatile("s_waitcnt vmcnt(4)" ::: "memory");   // certify stage 0
  const int NT = EMBED / 32;
  int buf = 0;
  for (int kt = 0; kt < NT; ++kt) {
    __builtin_amdgcn_s_barrier();          // everyone certified buf[kt]
    __builtin_amdgcn_sched_barrier(0);
    if (kt + 2 < NT) {
      int nb = buf + 2; if (nb >= 3) nb -= 3;
      STAGE(nb, kt + 2);
    }
    bf16x8 af[4], bfr[4];
#pragma unroll
    for (int ms = 0; ms < 4; ++ms)
      af[ms] = __builtin_bit_cast(bf16x8,
          *(const ushort8*)&Ab[buf * 4096 + (wy * 64 + ms * 16 + ln) * 32 + g * 8]);
#pragma unroll
    for (int ns = 0; ns < 4; ++ns)
      bfr[ns] = __builtin_bit_cast(bf16x8,
          *(const ushort8*)&Bb[buf * 4096 + (wx * 64 + ns * 16 + ln) * 32 + g * 8]);
#pragma unroll
    for (int ms = 0; ms < 4; ++ms)
#pragma unroll
      for (int ns = 0; ns < 4; ++ns)
        acc[ms][ns] = __builtin_amdgcn_mfma_f32_16x16x32_bf16(
            af[ms], bfr[ns], acc[ms][ns], 0, 0, 0);
    if (kt + 2 < NT) {
      asm volatile("s_waitcnt vmcnt(4)" ::: "memory");
    } else if (kt + 1 < NT) {
      asm volatile("s_waitcnt vmcnt(0)" ::: "memory");
    }
    buf = (buf == 2) ? 0 : buf + 1;
  }

  float bv[4];
#pragma unroll
  for (int ns = 0; ns < 4; ++ns) bv[ns] = bias[nbase + wx * 64 + ns * 16 + ln];

  if (OUT_MODE == 0) {
    unsigned short* out = (unsigned short*)outp;
#pragma unroll
    for (int ms = 0; ms < 4; ++ms)
#pragma unroll
      for (int ns = 0; ns < 4; ++ns) {
        int col = nbase + wx * 64 + ns * 16 + ln;
#pragma unroll
        for (int j = 0; j < 4; ++j) {
          int row = mbase + wy * 64 + ms * 16 + g * 4 + j;
          out[(size_t)row * EMBED + col] = f2bf(acc[ms][ns][j] + bv[ns]);
        }
      }
  } else if (OUT_MODE == 1) {
    unsigned short* out = (unsigned short*)outp;
#pragma unroll
    for (int ms = 0; ms < 4; ++ms)
#pragma unroll
      for (int ns = 0; ns < 4; ++ns) {
        int row0 = mbase + wy * 64 + ms * 16 + g * 4;
        int col = nbase + wx * 64 + ns * 16 + ln;
        int b = row0 >> 11, s0 = row0 & (SEQ - 1);
        int h = col >> 6, d = col & 63;
        ushort4v pk;
#pragma unroll
        for (int j = 0; j < 4; ++j) pk[j] = f2bf(acc[ms][ns][j] + bv[ns]);
        *(ushort4v*)&out[(size_t)((b * HEADS + h) * HDIM + d) * SEQ + s0] = pk;
      }
  } else {
    float* out = (float*)outp;
#pragma unroll
    for (int ms = 0; ms < 4; ++ms)
#pragma unroll
      for (int ns = 0; ns < 4; ++ns) {
        int col = nbase + wx * 64 + ns * 16 + ln;
#pragma unroll
        for (int j = 0; j < 4; ++j) {
          int row = mbase + wy * 64 + ms * 16 + g * 4 + j;
          out[(size_t)row * EMBED + col] = acc[ms][ns][j] + bv[ns];
        }
      }
  }
}

// ---- attention: triple-buffered K/V/mask, counted vmcnt, wait-then-barrier;
//      in-register P (T12); select masking; hoisted zero C-in; setprio ----
__global__ __launch_bounds__(512, 4) void attn7_kernel(
    const unsigned short* __restrict__ qp, const unsigned short* __restrict__ kp,
    const unsigned short* __restrict__ vpT,
    const unsigned long long* __restrict__ mask64,
    unsigned short* __restrict__ attb) {
  __shared__ __attribute__((aligned(16))) unsigned char lds[55296];
  unsigned char* Kb = lds;               // [3][64 rows][128B] swizzled
  unsigned char* Vb = lds + 24576;       // [3][64 rows][128B] swizzled
  unsigned char* Mb = lds + 49152;       // [3][256 rows][8B]

  const int tid = threadIdx.x;
  const int lane = tid & 63, wv = tid >> 6;
  const int lo = lane & 31, hi = lane >> 5;

  // XCD-aware decode: all 8 q-chunks of one (b,h) land on one XCD
  const int flat = blockIdx.x + 8 * blockIdx.y + 128 * blockIdx.z;   // 0..511
  const int bh = (flat & 7) * 8 + ((flat >> 3) & 7);
  const int qc = flat >> 6;
  const int b = bh >> 4, h = bh & 15;
  const int qb = qc * 256 + wv * 32;
  const int q = qb + lo;

  // ---- Q fragments, pre-scaled by SCL (so p = exp2(e) directly) ----
  bf16x8 qf[4];
  {
    const unsigned short* qr = qp + (size_t)(b * SEQ + q) * EMBED + h * HDIM + hi * 8;
#pragma unroll
    for (int c = 0; c < 4; ++c) {
      ushort8 u = *(const ushort8*)(qr + 16 * c);
      bf16x8 f;
#pragma unroll
      for (int j = 0; j < 8; ++j) {
        float x = __builtin_bit_cast(float, (unsigned)u[j] << 16) * SCL;
        f[j] = (__bf16)x;
      }
      qf[c] = f;
    }
  }

  // ---- staging: 512 threads; K,V: 16B each; mask: 4B each (256 rows x 8B) ----
  const int srow = tid >> 3;                        // 0..63
  const int srcc = ((tid & 7) * 16) ^ (((tid >> 3) & 7) << 4);  // inv swizzle
  const char* kbase = (const char*)kp
      + ((size_t)(b * SEQ + srow) * EMBED + h * HDIM) * 2 + srcc;
  const char* vbase = (const char*)vpT
      + ((size_t)((b * HEADS + h) * HDIM + srow)) * SEQ * 2 + srcc;
  const char* mgbase = (const char*)mask64
      + ((size_t)(b * SEQ + qc * 256 + (tid >> 1)) * 32) * 8 + (tid & 1) * 4;

  auto STAGE = [&](int buf, int kt) {
    GLD_LDS16(kbase + (size_t)kt * 64 * EMBED * 2, Kb + buf * 8192 + tid * 16);
    GLD_LDS16(vbase + (size_t)kt * 128, Vb + buf * 8192 + tid * 16);
    GLD_LDS4(mgbase + kt * 8, Mb + buf * 2048 + tid * 4);
  };

  f32x16 oacc0, oacc1, oacc2, z16;
#pragma unroll
  for (int i = 0; i < 16; ++i) {
    oacc0[i] = 0.f; oacc1[i] = 0.f; oacc2[i] = 0.f; z16[i] = 0.f;
  }
  bf16x8 ones;
#pragma unroll
  for (int j = 0; j < 8; ++j) ones[j] = (__bf16)1.0f;

  const int swz = (lo & 7) << 4;

  STAGE(0, 0);
  STAGE(1, 1);
  asm volatile("s_waitcnt vmcnt(3)" ::: "memory");   // certify stage 0
  const int NT = SEQ / 64;
  int buf = 0;
  for (int kt = 0; kt < NT; ++kt) {
    __builtin_amdgcn_s_barrier();          // everyone certified buf[kt]
    __builtin_amdgcn_sched_barrier(0);
    if (kt + 2 < NT) {
      int nb = buf + 2; if (nb >= 3) nb -= 3;
      STAGE(nb, kt + 2);
    }
    const unsigned char* Kc = Kb + buf * 8192;
    const unsigned char* Vc = Vb + buf * 8192;
    const unsigned long long mw =
        *(const unsigned long long*)(Mb + buf * 2048 + (wv * 32 + lo) * 8);

    // ---- QK^T (swapped: A=K, B=Q -> D[k][q]) + in-register P build ----
    bf16x8 PA[4];
#pragma unroll
    for (int kg = 0; kg < 2; ++kg) {
      f32x16 e;
      const int krow = kg * 32 + lo;
      __builtin_amdgcn_s_setprio(1);
#pragma unroll
      for (int c = 0; c < 4; ++c) {
        const int colb = (16 * c + 8 * hi) * 2;
        bf16x8 kf = *(const bf16x8*)(Kc + krow * 128 + (colb ^ swz));
        // first MFMA consumes the hoisted zero bank (no per-tile v_movs)
        e = __builtin_amdgcn_mfma_f32_32x32x16_bf16(kf, qf[c],
                                                    c == 0 ? z16 : e, 0, 0, 0);
      }
      __builtin_amdgcn_s_setprio(0);
      // mask + exp: p[4m+j] is k_local = 8m + 4hi + j; bit (8m+j) of mh
      const unsigned mh = (unsigned)(mw >> (kg * 32 + 4 * hi));
      float p[16];
#pragma unroll
      for (int m = 0; m < 4; ++m)
#pragma unroll
        for (int j = 0; j < 4; ++j) {
          float pe = __builtin_amdgcn_exp2f(e[4 * m + j]);
          p[4 * m + j] = (mh & (1u << (8 * m + j))) ? pe : 0.f;
        }
      // pack pairs to bf16; swap lane-halves: one permlane fills 2 words
      unsigned wA0 = cvtpk(p[0], p[1]),   wB0 = cvtpk(p[2], p[3]);
      unsigned wA1 = cvtpk(p[4], p[5]),   wB1 = cvtpk(p[6], p[7]);
      unsigned wA2 = cvtpk(p[8], p[9]),   wB2 = cvtpk(p[10], p[11]);
      unsigned wA3 = cvtpk(p[12], p[13]), wB3 = cvtpk(p[14], p[15]);
      asm("v_permlane32_swap_b32 %0, %1" : "+v"(wA0), "+v"(wA1));
      asm("v_permlane32_swap_b32 %0, %1" : "+v"(wB0), "+v"(wB1));
      asm("v_permlane32_swap_b32 %0, %1" : "+v"(wA2), "+v"(wA3));
      asm("v_permlane32_swap_b32 %0, %1" : "+v"(wB2), "+v"(wB3));
      PA[2 * kg]     = __builtin_bit_cast(bf16x8, (uint4v){wA0, wB0, wA1, wB1});
      PA[2 * kg + 1] = __builtin_bit_cast(bf16x8, (uint4v){wA2, wB2, wA3, wB3});
    }

    // ---- PV: A=P (in reg), B=V^T rows (d) -> D[q][d]; +ones denom ----
    __builtin_amdgcn_s_setprio(1);
#pragma unroll
    for (int c = 0; c < 4; ++c) {
      const int pcolb = 32 * c + 16 * hi;
      bf16x8 pf = PA[c];
      {
        bf16x8 vf = *(const bf16x8*)(Vc + lo * 128 + (pcolb ^ swz));
        oacc0 = __builtin_amdgcn_mfma_f32_32x32x16_bf16(pf, vf, oacc0, 0, 0, 0);
      }
      {
        const int drow = 32 + lo;
        bf16x8 vf = *(const bf16x8*)(Vc + drow * 128 + (pcolb ^ swz));
        oacc1 = __builtin_amdgcn_mfma_f32_32x32x16_bf16(pf, vf, oacc1, 0, 0, 0);
      }
      oacc2 = __builtin_amdgcn_mfma_f32_32x32x16_bf16(pf, ones, oacc2, 0, 0, 0);
    }
    __builtin_amdgcn_s_setprio(0);
    // certify stage kt+1 before next barrier; keep stage kt+2 in flight
    if (kt + 2 < NT) {
      asm volatile("s_waitcnt vmcnt(3)" ::: "memory");
    } else if (kt + 1 < NT) {
      asm volatile("s_waitcnt vmcnt(0)" ::: "memory");
    }
    buf = (buf == 2) ? 0 : buf + 1;
  }

  // ---- oacc2[r] = sum_k P[q_r][k] (same lane layout as oacc0) ----
#pragma unroll
  for (int r = 0; r < 16; ++r) {
    const int qq = qb + (r & 3) + 8 * (r >> 2) + 4 * hi;
    const float dinv = 1.0f / oacc2[r];
    unsigned short* orow = attb + (size_t)(b * SEQ + qq) * EMBED + h * HDIM;
    orow[lo] = f2bf(oacc0[r] * dinv);
    orow[32 + lo] = f2bf(oacc1[r] * dinv);
  }
}

extern "C" void kernel_launch(void* const* d_in, const int* in_sizes, int n_in,
                              void* d_out, int out_size, void* d_ws, size_t ws_size,
                              hipStream_t stream) {
  const float* q    = (const float*)d_in[0];
  const float* k    = (const float*)d_in[1];
  const float* v    = (const float*)d_in[2];
  const int*   mask = (const int*)d_in[3];
  const float* wq_w = (const float*)d_in[4];
  const float* wq_b = (const float*)d_in[5];
  const float* wk_w = (const float*)d_in[6];
  const float* wk_b = (const float*)d_in[7];
  const float* wv_w = (const float*)d_in[8];
  const float* wv_b = (const float*)d_in[9];
  const float* fo_w = (const float*)d_in[10];
  const float* fo_b = (const float*)d_in[11];

  // Workspace rotation (proven 74 MB footprint):
  //   regionA @0    (16MB): X_q bf16  -> later kp
  //   weights @16MB ( 8MB): wq/wk/wv/fo bf16
  //   regionB @24MB (16MB): X_k bf16  -> later vpT
  //   regionC @40MB (16MB): X_v bf16  -> later attn-out
  //   regionD @56MB (16MB): qp
  //   mask    @72MB ( 2MB): packed bits
  char* ws = (char*)d_ws;
  const size_t MB = 1024 * 1024;
  unsigned short* rA  = (unsigned short*)(ws);
  unsigned short* wqb = (unsigned short*)(ws + 16 * MB);
  unsigned short* rB  = (unsigned short*)(ws + 24 * MB);
  unsigned short* rC  = (unsigned short*)(ws + 40 * MB);
  unsigned short* rD  = (unsigned short*)(ws + 56 * MB);
  unsigned long long* m64 = (unsigned long long*)(ws + 72 * MB);

  const int NVX = BATCH * SEQ * EMBED / 8;   // 1048576 vec8
  const int NVW = EMBED * EMBED / 8;         // 131072 vec8

  // 1. pack mask bits (67MB -> 2MB, L3-resident for all 16 heads)
  pack_mask_kernel<<<(BATCH * SEQ * SEQ) / 256, 256, 0, stream>>>(mask, m64);

  // 2. weights -> bf16 (one launch; dsts contiguous)
  cvt4_kernel<<<dim3(NVW / 256, 4), 256, 0, stream>>>(wq_w, wk_w, wv_w, fo_w, wqb, NVW);
  unsigned short* wkb = wqb + (size_t)NVW * 8;
  unsigned short* wvb = wkb + (size_t)NVW * 8;
  unsigned short* fob = wvb + (size_t)NVW * 8;

  // 3. q,k,v -> bf16 (one launch)
  cvt3_kernel<<<dim3(NVX / 256, 3), 256, 0, stream>>>(q, k, v, rA, rB, rC, NVX);

  // 4-6. projections, back-to-back, rotating regions
  dim3 gg((BATCH * SEQ) / 128, EMBED / 128);
  gemm_bt<0><<<gg, 256, 0, stream>>>(rA, wqb, wq_b, rD);   // qp  = rD
  gemm_bt<0><<<gg, 256, 0, stream>>>(rB, wkb, wk_b, rA);   // kp  = rA
  gemm_bt<1><<<gg, 256, 0, stream>>>(rC, wvb, wv_b, rB);   // vpT = rB

  // 7. fused masked attention -> bf16 into rC
  attn7_kernel<<<dim3(8, HEADS, BATCH), 512, 0, stream>>>(rD, rA, rB, m64, rC);

  // 8. output projection -> d_out (f32)
  gemm_bt<2><<<gg, 256, 0, stream>>>(rC, fob, fo_b, (float*)d_out);
}

// Round 13
// 254.117 us; speedup vs baseline: 1.2124x; 1.0161x over previous
//
#include <hip/hip_runtime.h>

typedef __attribute__((ext_vector_type(4))) float f32x4;
typedef __attribute__((ext_vector_type(16))) float f32x16;
typedef __attribute__((ext_vector_type(8))) __bf16 bf16x8;
typedef __attribute__((ext_vector_type(8))) unsigned short ushort8;
typedef __attribute__((ext_vector_type(4))) unsigned short ushort4v;
typedef __attribute__((ext_vector_type(4))) unsigned uint4v;

#define EMBED 1024
#define SEQ   2048
#define BATCH 4
#define HEADS 16
#define HDIM  64
// log2(e) / sqrt(EMBED) : combines the 1/32 scale with exp->exp2
#define SCL 0.045084220027780106f

#define GLD_LDS16(g, l) __builtin_amdgcn_global_load_lds( \
    (const __attribute__((address_space(1))) void*)(g),   \
    (__attribute__((address_space(3))) void*)(l), 16, 0, 0)
#define GLD_LDS4(g, l) __builtin_amdgcn_global_load_lds(  \
    (const __attribute__((address_space(1))) void*)(g),   \
    (__attribute__((address_space(3))) void*)(l), 4, 0, 0)

static __device__ __forceinline__ unsigned short f2bf(float f) {
  unsigned u = __builtin_bit_cast(unsigned, f);
  u += 0x7FFFu + ((u >> 16) & 1u);   // RNE
  return (unsigned short)(u >> 16);
}
// packed f32x2 -> bf16x2 HW op (used ONLY for P, where uniform rounding
// bias cancels in the softmax ratio; NOT for GEMM operands)
static __device__ __forceinline__ unsigned cvtpk(float a, float b) {
  unsigned r;
  asm("v_cvt_pk_bf16_f32 %0, %1, %2" : "=v"(r) : "v"(a), "v"(b));
  return r;
}

// ---- merged prep: pack mask bits + weights->bf16 + q,k,v->bf16 ----
// blocks [0,65536): pack; [65536,67584): cvt4 weights; [67584,79872): cvt3 qkv
#define PREP_PACK_BLOCKS 65536
#define PREP_CVT4_BLOCKS 2048
#define PREP_CVT3_BLOCKS 12288
__global__ __launch_bounds__(256) void prep_kernel(
    const int* __restrict__ mask, unsigned long long* __restrict__ m64,
    const float* __restrict__ w0, const float* __restrict__ w1,
    const float* __restrict__ w2, const float* __restrict__ w3,
    unsigned short* __restrict__ wd,
    const float* __restrict__ q, const float* __restrict__ k,
    const float* __restrict__ v,
    unsigned short* __restrict__ dq, unsigned short* __restrict__ dk,
    unsigned short* __restrict__ dv) {
  const int bid = blockIdx.x;
  const int tid = threadIdx.x;
  if (bid < PREP_PACK_BLOCKS) {
    // pack int32 mask -> bitmask (bit k of word w = mask[w*64+k] != 0)
    int t = bid * 256 + tid;
    unsigned long long bits = __ballot(mask[t] != 0);
    if ((tid & 63) == 0) m64[t >> 6] = bits;
  } else if (bid < PREP_PACK_BLOCKS + PREP_CVT4_BLOCKS) {
    // weights -> bf16 (dsts contiguous at wd)
    int b2 = bid - PREP_PACK_BLOCKS;          // 0..2047
    int wsel = b2 >> 9;                        // 0..3
    int i = (b2 & 511) * 256 + tid;            // 0..NVW-1 (131072)
    const float* s = (wsel == 0) ? w0 : (wsel == 1) ? w1
                   : (wsel == 2) ? w2 : w3;
    unsigned short* dd = wd + (size_t)wsel * 131072 * 8;
    f32x4 a = ((const f32x4*)s)[2 * i];
    f32x4 b = ((const f32x4*)s)[2 * i + 1];
    ushort8 o;
#pragma unroll
    for (int j = 0; j < 4; ++j) { o[j] = f2bf(a[j]); o[4 + j] = f2bf(b[j]); }
    ((ushort8*)dd)[i] = o;
  } else {
    // q,k,v -> bf16
    int b3 = bid - PREP_PACK_BLOCKS - PREP_CVT4_BLOCKS;  // 0..12287
    int xsel = b3 >> 12;                       // 0..2
    int i = (b3 & 4095) * 256 + tid;           // 0..NVX-1 (1048576)
    const float* s = (xsel == 0) ? q : (xsel == 1) ? k : v;
    unsigned short* d = (xsel == 0) ? dq : (xsel == 1) ? dk : dv;
    f32x4 a = ((const f32x4*)s)[2 * i];
    f32x4 b = ((const f32x4*)s)[2 * i + 1];
    ushort8 o;
#pragma unroll
    for (int j = 0; j < 4; ++j) { o[j] = f2bf(a[j]); o[4 + j] = f2bf(b[j]); }
    ((ushort8*)d)[i] = o;
  }
}

// ---- C[M x 1024] = A[M x 1024](bf16) @ B[1024 x 1024](bf16)^T + bias ----
// 128x128 tile, BK=32, global_load_lds w16, triple buffer, counted vmcnt,
// WAIT-THEN-BARRIER discipline (race-free, verified rounds 8/10/11).
// OUT_MODE 0: bf16 row-major   1: bf16 vpT[b][h][d][s]   2: f32 row-major
template<int OUT_MODE>
__global__ __launch_bounds__(256, 3) void gemm_bt(
    const unsigned short* __restrict__ A, const unsigned short* __restrict__ B,
    const float* __restrict__ bias, void* __restrict__ outp) {
  __shared__ __attribute__((aligned(16))) unsigned short Ab[3 * 128 * 32];
  __shared__ __attribute__((aligned(16))) unsigned short Bb[3 * 128 * 32];
  const int tid = threadIdx.x, lane = tid & 63, wv = tid >> 6;
  const int wy = wv >> 1, wx = wv & 1, ln = lane & 15, g = lane >> 4;
  const int mbase = blockIdx.x * 128, nbase = blockIdx.y * 128;

  const char* Ag = (const char*)(A + (size_t)(mbase + (tid >> 2)) * EMBED)
                   + (tid & 3) * 16;
  const char* Bg = (const char*)(B + (size_t)(nbase + (tid >> 2)) * EMBED)
                   + (tid & 3) * 16;
  const size_t R64B = (size_t)64 * EMBED * 2;

  f32x4 acc[4][4];
#pragma unroll
  for (int i = 0; i < 4; i++)
#pragma unroll
    for (int j = 0; j < 4; j++) acc[i][j] = (f32x4){0.f, 0.f, 0.f, 0.f};

  auto STAGE = [&](int buf, int kt) {
    const size_t koff = (size_t)kt * 64;   // BK=32 bf16 = 64 bytes
    char* al = (char*)Ab + buf * 8192 + tid * 16;
    char* bl = (char*)Bb + buf * 8192 + tid * 16;
    GLD_LDS16(Ag + koff, al);
    GLD_LDS16(Ag + koff + R64B, al + 4096);
    GLD_LDS16(Bg + koff, bl);
    GLD_LDS16(Bg + koff + R64B, bl + 4096);
  };

  STAGE(0, 0);
  STAGE(1, 1);
  asm volatile("s_waitcnt vmcnt(4)" ::: "memory");   // certify stage 0
  const int NT = EMBED / 32;
  int buf = 0;
  for (int kt = 0; kt < NT; ++kt) {
    __builtin_amdgcn_s_barrier();          // everyone certified buf[kt]
    __builtin_amdgcn_sched_barrier(0);
    if (kt + 2 < NT) {
      int nb = buf + 2; if (nb >= 3) nb -= 3;
      STAGE(nb, kt + 2);
    }
    bf16x8 af[4], bfr[4];
#pragma unroll
    for (int ms = 0; ms < 4; ++ms)
      af[ms] = __builtin_bit_cast(bf16x8,
          *(const ushort8*)&Ab[buf * 4096 + (wy * 64 + ms * 16 + ln) * 32 + g * 8]);
#pragma unroll
    for (int ns = 0; ns < 4; ++ns)
      bfr[ns] = __builtin_bit_cast(bf16x8,
          *(const ushort8*)&Bb[buf * 4096 + (wx * 64 + ns * 16 + ln) * 32 + g * 8]);
#pragma unroll
    for (int ms = 0; ms < 4; ++ms)
#pragma unroll
      for (int ns = 0; ns < 4; ++ns)
        acc[ms][ns] = __builtin_amdgcn_mfma_f32_16x16x32_bf16(
            af[ms], bfr[ns], acc[ms][ns], 0, 0, 0);
    if (kt + 2 < NT) {
      asm volatile("s_waitcnt vmcnt(4)" ::: "memory");
    } else if (kt + 1 < NT) {
      asm volatile("s_waitcnt vmcnt(0)" ::: "memory");
    }
    buf = (buf == 2) ? 0 : buf + 1;
  }

  float bv[4];
#pragma unroll
  for (int ns = 0; ns < 4; ++ns) bv[ns] = bias[nbase + wx * 64 + ns * 16 + ln];

  if (OUT_MODE == 0) {
    unsigned short* out = (unsigned short*)outp;
#pragma unroll
    for (int ms = 0; ms < 4; ++ms)
#pragma unroll
      for (int ns = 0; ns < 4; ++ns) {
        int col = nbase + wx * 64 + ns * 16 + ln;
#pragma unroll
        for (int j = 0; j < 4; ++j) {
          int row = mbase + wy * 64 + ms * 16 + g * 4 + j;
          out[(size_t)row * EMBED + col] = f2bf(acc[ms][ns][j] + bv[ns]);
        }
      }
  } else if (OUT_MODE == 1) {
    unsigned short* out = (unsigned short*)outp;
#pragma unroll
    for (int ms = 0; ms < 4; ++ms)
#pragma unroll
      for (int ns = 0; ns < 4; ++ns) {
        int row0 = mbase + wy * 64 + ms * 16 + g * 4;
        int col = nbase + wx * 64 + ns * 16 + ln;
        int b = row0 >> 11, s0 = row0 & (SEQ - 1);
        int h = col >> 6, d = col & 63;
        ushort4v pk;
#pragma unroll
        for (int j = 0; j < 4; ++j) pk[j] = f2bf(acc[ms][ns][j] + bv[ns]);
        *(ushort4v*)&out[(size_t)((b * HEADS + h) * HDIM + d) * SEQ + s0] = pk;
      }
  } else {
    float* out = (float*)outp;
#pragma unroll
    for (int ms = 0; ms < 4; ++ms)
#pragma unroll
      for (int ns = 0; ns < 4; ++ns) {
        int col = nbase + wx * 64 + ns * 16 + ln;
#pragma unroll
        for (int j = 0; j < 4; ++j) {
          int row = mbase + wy * 64 + ms * 16 + g * 4 + j;
          out[(size_t)row * EMBED + col] = acc[ms][ns][j] + bv[ns];
        }
      }
  }
}

// ---- attention (round-11 verbatim): triple-buffered K/V/mask, counted
//      vmcnt, wait-then-barrier; in-register P (T12); select masking ----
__global__ __launch_bounds__(512, 4) void attn7_kernel(
    const unsigned short* __restrict__ qp, const unsigned short* __restrict__ kp,
    const unsigned short* __restrict__ vpT,
    const unsigned long long* __restrict__ mask64,
    unsigned short* __restrict__ attb) {
  __shared__ __attribute__((aligned(16))) unsigned char lds[55296];
  unsigned char* Kb = lds;               // [3][64 rows][128B] swizzled
  unsigned char* Vb = lds + 24576;       // [3][64 rows][128B] swizzled
  unsigned char* Mb = lds + 49152;       // [3][256 rows][8B]

  const int tid = threadIdx.x;
  const int lane = tid & 63, wv = tid >> 6;
  const int lo = lane & 31, hi = lane >> 5;

  // XCD-aware decode: all 8 q-chunks of one (b,h) land on one XCD
  const int flat = blockIdx.x + 8 * blockIdx.y + 128 * blockIdx.z;   // 0..511
  const int bh = (flat & 7) * 8 + ((flat >> 3) & 7);
  const int qc = flat >> 6;
  const int b = bh >> 4, h = bh & 15;
  const int qb = qc * 256 + wv * 32;
  const int q = qb + lo;

  // ---- Q fragments, pre-scaled by SCL (so p = exp2(e) directly) ----
  bf16x8 qf[4];
  {
    const unsigned short* qr = qp + (size_t)(b * SEQ + q) * EMBED + h * HDIM + hi * 8;
#pragma unroll
    for (int c = 0; c < 4; ++c) {
      ushort8 u = *(const ushort8*)(qr + 16 * c);
      bf16x8 f;
#pragma unroll
      for (int j = 0; j < 8; ++j) {
        float x = __builtin_bit_cast(float, (unsigned)u[j] << 16) * SCL;
        f[j] = (__bf16)x;
      }
      qf[c] = f;
    }
  }

  // ---- staging: 512 threads; K,V: 16B each; mask: 4B each (256 rows x 8B) ----
  const int srow = tid >> 3;                        // 0..63
  const int srcc = ((tid & 7) * 16) ^ (((tid >> 3) & 7) << 4);  // inv swizzle
  const char* kbase = (const char*)kp
      + ((size_t)(b * SEQ + srow) * EMBED + h * HDIM) * 2 + srcc;
  const char* vbase = (const char*)vpT
      + ((size_t)((b * HEADS + h) * HDIM + srow)) * SEQ * 2 + srcc;
  const char* mgbase = (const char*)mask64
      + ((size_t)(b * SEQ + qc * 256 + (tid >> 1)) * 32) * 8 + (tid & 1) * 4;

  auto STAGE = [&](int buf, int kt) {
    GLD_LDS16(kbase + (size_t)kt * 64 * EMBED * 2, Kb + buf * 8192 + tid * 16);
    GLD_LDS16(vbase + (size_t)kt * 128, Vb + buf * 8192 + tid * 16);
    GLD_LDS4(mgbase + kt * 8, Mb + buf * 2048 + tid * 4);
  };

  f32x16 oacc0, oacc1, oacc2, z16;
#pragma unroll
  for (int i = 0; i < 16; ++i) {
    oacc0[i] = 0.f; oacc1[i] = 0.f; oacc2[i] = 0.f; z16[i] = 0.f;
  }
  bf16x8 ones;
#pragma unroll
  for (int j = 0; j < 8; ++j) ones[j] = (__bf16)1.0f;

  const int swz = (lo & 7) << 4;

  STAGE(0, 0);
  STAGE(1, 1);
  asm volatile("s_waitcnt vmcnt(3)" ::: "memory");   // certify stage 0
  const int NT = SEQ / 64;
  int buf = 0;
  for (int kt = 0; kt < NT; ++kt) {
    __builtin_amdgcn_s_barrier();          // everyone certified buf[kt]
    __builtin_amdgcn_sched_barrier(0);
    if (kt + 2 < NT) {
      int nb = buf + 2; if (nb >= 3) nb -= 3;
      STAGE(nb, kt + 2);
    }
    const unsigned char* Kc = Kb + buf * 8192;
    const unsigned char* Vc = Vb + buf * 8192;
    const unsigned long long mw =
        *(const unsigned long long*)(Mb + buf * 2048 + (wv * 32 + lo) * 8);

    // ---- QK^T (swapped: A=K, B=Q -> D[k][q]) + in-register P build ----
    bf16x8 PA[4];
#pragma unroll
    for (int kg = 0; kg < 2; ++kg) {
      f32x16 e;
      const int krow = kg * 32 + lo;
      __builtin_amdgcn_s_setprio(1);
#pragma unroll
      for (int c = 0; c < 4; ++c) {
        const int colb = (16 * c + 8 * hi) * 2;
        bf16x8 kf = *(const bf16x8*)(Kc + krow * 128 + (colb ^ swz));
        // first MFMA consumes the hoisted zero bank (no per-tile v_movs)
        e = __builtin_amdgcn_mfma_f32_32x32x16_bf16(kf, qf[c],
                                                    c == 0 ? z16 : e, 0, 0, 0);
      }
      __builtin_amdgcn_s_setprio(0);
      // mask + exp: p[4m+j] is k_local = 8m + 4hi + j; bit (8m+j) of mh
      const unsigned mh = (unsigned)(mw >> (kg * 32 + 4 * hi));
      float p[16];
#pragma unroll
      for (int m = 0; m < 4; ++m)
#pragma unroll
        for (int j = 0; j < 4; ++j) {
          float pe = __builtin_amdgcn_exp2f(e[4 * m + j]);
          p[4 * m + j] = (mh & (1u << (8 * m + j))) ? pe : 0.f;
        }
      // pack pairs to bf16; swap lane-halves: one permlane fills 2 words
      unsigned wA0 = cvtpk(p[0], p[1]),   wB0 = cvtpk(p[2], p[3]);
      unsigned wA1 = cvtpk(p[4], p[5]),   wB1 = cvtpk(p[6], p[7]);
      unsigned wA2 = cvtpk(p[8], p[9]),   wB2 = cvtpk(p[10], p[11]);
      unsigned wA3 = cvtpk(p[12], p[13]), wB3 = cvtpk(p[14], p[15]);
      asm("v_permlane32_swap_b32 %0, %1" : "+v"(wA0), "+v"(wA1));
      asm("v_permlane32_swap_b32 %0, %1" : "+v"(wB0), "+v"(wB1));
      asm("v_permlane32_swap_b32 %0, %1" : "+v"(wA2), "+v"(wA3));
      asm("v_permlane32_swap_b32 %0, %1" : "+v"(wB2), "+v"(wB3));
      PA[2 * kg]     = __builtin_bit_cast(bf16x8, (uint4v){wA0, wB0, wA1, wB1});
      PA[2 * kg + 1] = __builtin_bit_cast(bf16x8, (uint4v){wA2, wB2, wA3, wB3});
    }

    // ---- PV: A=P (in reg), B=V^T rows (d) -> D[q][d]; +ones denom ----
    __builtin_amdgcn_s_setprio(1);
#pragma unroll
    for (int c = 0; c < 4; ++c) {
      const int pcolb = 32 * c + 16 * hi;
      bf16x8 pf = PA[c];
      {
        bf16x8 vf = *(const bf16x8*)(Vc + lo * 128 + (pcolb ^ swz));
        oacc0 = __builtin_amdgcn_mfma_f32_32x32x16_bf16(pf, vf, oacc0, 0, 0, 0);
      }
      {
        const int drow = 32 + lo;
        bf16x8 vf = *(const bf16x8*)(Vc + drow * 128 + (pcolb ^ swz));
        oacc1 = __builtin_amdgcn_mfma_f32_32x32x16_bf16(pf, vf, oacc1, 0, 0, 0);
      }
      oacc2 = __builtin_amdgcn_mfma_f32_32x32x16_bf16(pf, ones, oacc2, 0, 0, 0);
    }
    __builtin_amdgcn_s_setprio(0);
    // certify stage kt+1 before next barrier; keep stage kt+2 in flight
    if (kt + 2 < NT) {
      asm volatile("s_waitcnt vmcnt(3)" ::: "memory");
    } else if (kt + 1 < NT) {
      asm volatile("s_waitcnt vmcnt(0)" ::: "memory");
    }
    buf = (buf == 2) ? 0 : buf + 1;
  }

  // ---- oacc2[r] = sum_k P[q_r][k] (same lane layout as oacc0) ----
#pragma unroll
  for (int r = 0; r < 16; ++r) {
    const int qq = qb + (r & 3) + 8 * (r >> 2) + 4 * hi;
    const float dinv = 1.0f / oacc2[r];
    unsigned short* orow = attb + (size_t)(b * SEQ + qq) * EMBED + h * HDIM;
    orow[lo] = f2bf(oacc0[r] * dinv);
    orow[32 + lo] = f2bf(oacc1[r] * dinv);
  }
}

extern "C" void kernel_launch(void* const* d_in, const int* in_sizes, int n_in,
                              void* d_out, int out_size, void* d_ws, size_t ws_size,
                              hipStream_t stream) {
  const float* q    = (const float*)d_in[0];
  const float* k    = (const float*)d_in[1];
  const float* v    = (const float*)d_in[2];
  const int*   mask = (const int*)d_in[3];
  const float* wq_w = (const float*)d_in[4];
  const float* wq_b = (const float*)d_in[5];
  const float* wk_w = (const float*)d_in[6];
  const float* wk_b = (const float*)d_in[7];
  const float* wv_w = (const float*)d_in[8];
  const float* wv_b = (const float*)d_in[9];
  const float* fo_w = (const float*)d_in[10];
  const float* fo_b = (const float*)d_in[11];

  // Workspace rotation (proven 74 MB footprint):
  //   regionA @0    (16MB): X_q bf16  -> later kp
  //   weights @16MB ( 8MB): wq/wk/wv/fo bf16
  //   regionB @24MB (16MB): X_k bf16  -> later vpT
  //   regionC @40MB (16MB): X_v bf16  -> later attn-out
  //   regionD @56MB (16MB): qp
  //   mask    @72MB ( 2MB): packed bits
  char* ws = (char*)d_ws;
  const size_t MB = 1024 * 1024;
  unsigned short* rA  = (unsigned short*)(ws);
  unsigned short* wqb = (unsigned short*)(ws + 16 * MB);
  unsigned short* rB  = (unsigned short*)(ws + 24 * MB);
  unsigned short* rC  = (unsigned short*)(ws + 40 * MB);
  unsigned short* rD  = (unsigned short*)(ws + 56 * MB);
  unsigned long long* m64 = (unsigned long long*)(ws + 72 * MB);

  const int NVW = EMBED * EMBED / 8;         // 131072 vec8

  // 1. merged prep: pack mask + weights->bf16 + q,k,v->bf16 (one launch)
  prep_kernel<<<PREP_PACK_BLOCKS + PREP_CVT4_BLOCKS + PREP_CVT3_BLOCKS,
                256, 0, stream>>>(
      mask, m64, wq_w, wk_w, wv_w, fo_w, wqb, q, k, v, rA, rB, rC);
  unsigned short* wkb = wqb + (size_t)NVW * 8;
  unsigned short* wvb = wkb + (size_t)NVW * 8;
  unsigned short* fob = wvb + (size_t)NVW * 8;

  // 2-4. projections, back-to-back, rotating regions
  dim3 gg((BATCH * SEQ) / 128, EMBED / 128);
  gemm_bt<0><<<gg, 256, 0, stream>>>(rA, wqb, wq_b, rD);   // qp  = rD
  gemm_bt<0><<<gg, 256, 0, stream>>>(rB, wkb, wk_b, rA);   // kp  = rA
  gemm_bt<1><<<gg, 256, 0, stream>>>(rC, wvb, wv_b, rB);   // vpT = rB

  // 5. fused masked attention -> bf16 into rC
  attn7_kernel<<<dim3(8, HEADS, BATCH), 512, 0, stream>>>(rD, rA, rB, m64, rC);

  // 6. output projection -> d_out (f32)
  gemm_bt<2><<<gg, 256, 0, stream>>>(rC, fob, fo_b, (float*)d_out);
}

// Round 14
// 239.871 us; speedup vs baseline: 1.2844x; 1.0594x over previous
//
#include <hip/hip_runtime.h>

typedef __attribute__((ext_vector_type(4))) float f32x4;
typedef __attribute__((ext_vector_type(16))) float f32x16;
typedef __attribute__((ext_vector_type(8))) __bf16 bf16x8;
typedef __attribute__((ext_vector_type(8))) unsigned short ushort8;
typedef __attribute__((ext_vector_type(4))) unsigned short ushort4v;
typedef __attribute__((ext_vector_type(4))) unsigned uint4v;

#define EMBED 1024
#define SEQ   2048
#define BATCH 4
#define HEADS 16
#define HDIM  64
// log2(e) / sqrt(EMBED) : combines the 1/32 scale with exp->exp2
#define SCL 0.045084220027780106f

#define GLD_LDS16(g, l) __builtin_amdgcn_global_load_lds( \
    (const __attribute__((address_space(1))) void*)(g),   \
    (__attribute__((address_space(3))) void*)(l), 16, 0, 0)
#define GLD_LDS4(g, l) __builtin_amdgcn_global_load_lds(  \
    (const __attribute__((address_space(1))) void*)(g),   \
    (__attribute__((address_space(3))) void*)(l), 4, 0, 0)

static __device__ __forceinline__ unsigned short f2bf(float f) {
  unsigned u = __builtin_bit_cast(unsigned, f);
  u += 0x7FFFu + ((u >> 16) & 1u);   // RNE
  return (unsigned short)(u >> 16);
}
// packed f32x2 -> bf16x2 HW op (used ONLY for P, where uniform rounding
// bias cancels in the softmax ratio; NOT for GEMM operands)
static __device__ __forceinline__ unsigned cvtpk(float a, float b) {
  unsigned r;
  asm("v_cvt_pk_bf16_f32 %0, %1, %2" : "=v"(r) : "v"(a), "v"(b));
  return r;
}

// ---- merged prep: pack mask bits + weights->bf16 + q,k,v->bf16 ----
// blocks [0,65536): pack; [65536,67584): cvt4 weights; [67584,79872): cvt3 qkv
#define PREP_PACK_BLOCKS 65536
#define PREP_CVT4_BLOCKS 2048
#define PREP_CVT3_BLOCKS 12288
__global__ __launch_bounds__(256) void prep_kernel(
    const int* __restrict__ mask, unsigned long long* __restrict__ m64,
    const float* __restrict__ w0, const float* __restrict__ w1,
    const float* __restrict__ w2, const float* __restrict__ w3,
    unsigned short* __restrict__ wd,
    const float* __restrict__ q, const float* __restrict__ k,
    const float* __restrict__ v,
    unsigned short* __restrict__ dq, unsigned short* __restrict__ dk,
    unsigned short* __restrict__ dv) {
  const int bid = blockIdx.x;
  const int tid = threadIdx.x;
  if (bid < PREP_PACK_BLOCKS) {
    int t = bid * 256 + tid;
    unsigned long long bits = __ballot(mask[t] != 0);
    if ((tid & 63) == 0) m64[t >> 6] = bits;
  } else if (bid < PREP_PACK_BLOCKS + PREP_CVT4_BLOCKS) {
    int b2 = bid - PREP_PACK_BLOCKS;          // 0..2047
    int wsel = b2 >> 9;                        // 0..3
    int i = (b2 & 511) * 256 + tid;            // 0..NVW-1 (131072)
    const float* s = (wsel == 0) ? w0 : (wsel == 1) ? w1
                   : (wsel == 2) ? w2 : w3;
    unsigned short* dd = wd + (size_t)wsel * 131072 * 8;
    f32x4 a = ((const f32x4*)s)[2 * i];
    f32x4 b = ((const f32x4*)s)[2 * i + 1];
    ushort8 o;
#pragma unroll
    for (int j = 0; j < 4; ++j) { o[j] = f2bf(a[j]); o[4 + j] = f2bf(b[j]); }
    ((ushort8*)dd)[i] = o;
  } else {
    int b3 = bid - PREP_PACK_BLOCKS - PREP_CVT4_BLOCKS;  // 0..12287
    int xsel = b3 >> 12;                       // 0..2
    int i = (b3 & 4095) * 256 + tid;           // 0..NVX-1 (1048576)
    const float* s = (xsel == 0) ? q : (xsel == 1) ? k : v;
    unsigned short* d = (xsel == 0) ? dq : (xsel == 1) ? dk : dv;
    f32x4 a = ((const f32x4*)s)[2 * i];
    f32x4 b = ((const f32x4*)s)[2 * i + 1];
    ushort8 o;
#pragma unroll
    for (int j = 0; j < 4; ++j) { o[j] = f2bf(a[j]); o[4 + j] = f2bf(b[j]); }
    ((ushort8*)d)[i] = o;
  }
}

// ---- shared GEMM body (verified R8/R10/R11/R13): 128x128 tile, BK=32,
// global_load_lds w16, triple buffer, counted vmcnt, wait-then-barrier. ----
// Computes acc for C-tile (mbase,nbase) of A @ B^T. Epilogue done by caller.
template<typename ACC>
static __device__ __forceinline__ void gemm_body(
    const unsigned short* __restrict__ A, const unsigned short* __restrict__ B,
    int mbase, int nbase, int tid, int wy, int wx, int ln, int g,
    unsigned short* Ab, unsigned short* Bb, ACC& acc) {
  const char* Ag = (const char*)(A + (size_t)(mbase + (tid >> 2)) * EMBED)
                   + (tid & 3) * 16;
  const char* Bg = (const char*)(B + (size_t)(nbase + (tid >> 2)) * EMBED)
                   + (tid & 3) * 16;
  const size_t R64B = (size_t)64 * EMBED * 2;

  auto STAGE = [&](int buf, int kt) {
    const size_t koff = (size_t)kt * 64;   // BK=32 bf16 = 64 bytes
    char* al = (char*)Ab + buf * 8192 + tid * 16;
    char* bl = (char*)Bb + buf * 8192 + tid * 16;
    GLD_LDS16(Ag + koff, al);
    GLD_LDS16(Ag + koff + R64B, al + 4096);
    GLD_LDS16(Bg + koff, bl);
    GLD_LDS16(Bg + koff + R64B, bl + 4096);
  };

  STAGE(0, 0);
  STAGE(1, 1);
  asm volatile("s_waitcnt vmcnt(4)" ::: "memory");   // certify stage 0
  const int NT = EMBED / 32;
  int buf = 0;
  for (int kt = 0; kt < NT; ++kt) {
    __builtin_amdgcn_s_barrier();          // everyone certified buf[kt]
    __builtin_amdgcn_sched_barrier(0);
    if (kt + 2 < NT) {
      int nb = buf + 2; if (nb >= 3) nb -= 3;
      STAGE(nb, kt + 2);
    }
    bf16x8 af[4], bfr[4];
#pragma unroll
    for (int ms = 0; ms < 4; ++ms)
      af[ms] = __builtin_bit_cast(bf16x8,
          *(const ushort8*)&Ab[buf * 4096 + (wy * 64 + ms * 16 + ln) * 32 + g * 8]);
#pragma unroll
    for (int ns = 0; ns < 4; ++ns)
      bfr[ns] = __builtin_bit_cast(bf16x8,
          *(const ushort8*)&Bb[buf * 4096 + (wx * 64 + ns * 16 + ln) * 32 + g * 8]);
#pragma unroll
    for (int ms = 0; ms < 4; ++ms)
#pragma unroll
      for (int ns = 0; ns < 4; ++ns)
        acc[ms][ns] = __builtin_amdgcn_mfma_f32_16x16x32_bf16(
            af[ms], bfr[ns], acc[ms][ns], 0, 0, 0);
    if (kt + 2 < NT) {
      asm volatile("s_waitcnt vmcnt(4)" ::: "memory");
    } else if (kt + 1 < NT) {
      asm volatile("s_waitcnt vmcnt(0)" ::: "memory");
    }
    buf = (buf == 2) ? 0 : buf + 1;
  }
}

// ---- single GEMM: C[M x 1024] = A @ B^T + bias ----
// OUT_MODE 0: bf16 row-major   1: bf16 vpT[b][h][d][s]   2: f32 row-major
template<int OUT_MODE>
__global__ __launch_bounds__(256, 3) void gemm_bt(
    const unsigned short* __restrict__ A, const unsigned short* __restrict__ B,
    const float* __restrict__ bias, void* __restrict__ outp) {
  __shared__ __attribute__((aligned(16))) unsigned short Ab[3 * 128 * 32];
  __shared__ __attribute__((aligned(16))) unsigned short Bb[3 * 128 * 32];
  const int tid = threadIdx.x, lane = tid & 63, wv = tid >> 6;
  const int wy = wv >> 1, wx = wv & 1, ln = lane & 15, g = lane >> 4;
  const int mbase = blockIdx.x * 128, nbase = blockIdx.y * 128;

  f32x4 acc[4][4];
#pragma unroll
  for (int i = 0; i < 4; i++)
#pragma unroll
    for (int j = 0; j < 4; j++) acc[i][j] = (f32x4){0.f, 0.f, 0.f, 0.f};

  gemm_body(A, B, mbase, nbase, tid, wy, wx, ln, g, Ab, Bb, acc);

  float bv[4];
#pragma unroll
  for (int ns = 0; ns < 4; ++ns) bv[ns] = bias[nbase + wx * 64 + ns * 16 + ln];

  if (OUT_MODE == 0) {
    unsigned short* out = (unsigned short*)outp;
#pragma unroll
    for (int ms = 0; ms < 4; ++ms)
#pragma unroll
      for (int ns = 0; ns < 4; ++ns) {
        int col = nbase + wx * 64 + ns * 16 + ln;
#pragma unroll
        for (int j = 0; j < 4; ++j) {
          int row = mbase + wy * 64 + ms * 16 + g * 4 + j;
          out[(size_t)row * EMBED + col] = f2bf(acc[ms][ns][j] + bv[ns]);
        }
      }
  } else if (OUT_MODE == 1) {
    unsigned short* out = (unsigned short*)outp;
#pragma unroll
    for (int ms = 0; ms < 4; ++ms)
#pragma unroll
      for (int ns = 0; ns < 4; ++ns) {
        int row0 = mbase + wy * 64 + ms * 16 + g * 4;
        int col = nbase + wx * 64 + ns * 16 + ln;
        int b = row0 >> 11, s0 = row0 & (SEQ - 1);
        int h = col >> 6, d = col & 63;
        ushort4v pk;
#pragma unroll
        for (int j = 0; j < 4; ++j) pk[j] = f2bf(acc[ms][ns][j] + bv[ns]);
        *(ushort4v*)&out[(size_t)((b * HEADS + h) * HDIM + d) * SEQ + s0] = pk;
      }
  } else {
    float* out = (float*)outp;
#pragma unroll
    for (int ms = 0; ms < 4; ++ms)
#pragma unroll
      for (int ns = 0; ns < 4; ++ns) {
        int col = nbase + wx * 64 + ns * 16 + ln;
#pragma unroll
        for (int j = 0; j < 4; ++j) {
          int row = mbase + wy * 64 + ms * 16 + g * 4 + j;
          out[(size_t)row * EMBED + col] = acc[ms][ns][j] + bv[ns];
        }
      }
  }
}

// ---- merged QKV projections: blockIdx.z selects {q,k,v}; z<2 -> row-major
// bf16 out, z=2 -> vpT out. Body identical to gemm_bt. Outputs are fresh
// regions (no aliasing with any input of this launch). ----
__global__ __launch_bounds__(256, 3) void gemm_qkv(
    const unsigned short* __restrict__ A0, const unsigned short* __restrict__ A1,
    const unsigned short* __restrict__ A2, const unsigned short* __restrict__ Bw,
    const float* __restrict__ b0, const float* __restrict__ b1,
    const float* __restrict__ b2,
    unsigned short* __restrict__ o0, unsigned short* __restrict__ o1,
    unsigned short* __restrict__ o2) {
  __shared__ __attribute__((aligned(16))) unsigned short Ab[3 * 128 * 32];
  __shared__ __attribute__((aligned(16))) unsigned short Bb[3 * 128 * 32];
  const int tid = threadIdx.x, lane = tid & 63, wv = tid >> 6;
  const int wy = wv >> 1, wx = wv & 1, ln = lane & 15, g = lane >> 4;
  const int mbase = blockIdx.x * 128, nbase = blockIdx.y * 128;
  const int zz = blockIdx.z;

  const unsigned short* A = (zz == 0) ? A0 : (zz == 1) ? A1 : A2;
  const unsigned short* B = Bw + (size_t)zz * EMBED * EMBED;
  const float* bias = (zz == 0) ? b0 : (zz == 1) ? b1 : b2;

  f32x4 acc[4][4];
#pragma unroll
  for (int i = 0; i < 4; i++)
#pragma unroll
    for (int j = 0; j < 4; j++) acc[i][j] = (f32x4){0.f, 0.f, 0.f, 0.f};

  gemm_body(A, B, mbase, nbase, tid, wy, wx, ln, g, Ab, Bb, acc);

  float bv[4];
#pragma unroll
  for (int ns = 0; ns < 4; ++ns) bv[ns] = bias[nbase + wx * 64 + ns * 16 + ln];

  if (zz < 2) {
    unsigned short* out = (zz == 0) ? o0 : o1;
#pragma unroll
    for (int ms = 0; ms < 4; ++ms)
#pragma unroll
      for (int ns = 0; ns < 4; ++ns) {
        int col = nbase + wx * 64 + ns * 16 + ln;
#pragma unroll
        for (int j = 0; j < 4; ++j) {
          int row = mbase + wy * 64 + ms * 16 + g * 4 + j;
          out[(size_t)row * EMBED + col] = f2bf(acc[ms][ns][j] + bv[ns]);
        }
      }
  } else {
    unsigned short* out = o2;
#pragma unroll
    for (int ms = 0; ms < 4; ++ms)
#pragma unroll
      for (int ns = 0; ns < 4; ++ns) {
        int row0 = mbase + wy * 64 + ms * 16 + g * 4;
        int col = nbase + wx * 64 + ns * 16 + ln;
        int b = row0 >> 11, s0 = row0 & (SEQ - 1);
        int h = col >> 6, d = col & 63;
        ushort4v pk;
#pragma unroll
        for (int j = 0; j < 4; ++j) pk[j] = f2bf(acc[ms][ns][j] + bv[ns]);
        *(ushort4v*)&out[(size_t)((b * HEADS + h) * HDIM + d) * SEQ + s0] = pk;
      }
  }
}

// ---- attention (verified R8/R10/R11/R13): triple-buffered K/V/mask, counted
//      vmcnt, wait-then-barrier; in-register P (T12); select masking ----
__global__ __launch_bounds__(512, 4) void attn7_kernel(
    const unsigned short* __restrict__ qp, const unsigned short* __restrict__ kp,
    const unsigned short* __restrict__ vpT,
    const unsigned long long* __restrict__ mask64,
    unsigned short* __restrict__ attb) {
  __shared__ __attribute__((aligned(16))) unsigned char lds[55296];
  unsigned char* Kb = lds;               // [3][64 rows][128B] swizzled
  unsigned char* Vb = lds + 24576;       // [3][64 rows][128B] swizzled
  unsigned char* Mb = lds + 49152;       // [3][256 rows][8B]

  const int tid = threadIdx.x;
  const int lane = tid & 63, wv = tid >> 6;
  const int lo = lane & 31, hi = lane >> 5;

  // XCD-aware decode: all 8 q-chunks of one (b,h) land on one XCD
  const int flat = blockIdx.x + 8 * blockIdx.y + 128 * blockIdx.z;   // 0..511
  const int bh = (flat & 7) * 8 + ((flat >> 3) & 7);
  const int qc = flat >> 6;
  const int b = bh >> 4, h = bh & 15;
  const int qb = qc * 256 + wv * 32;
  const int q = qb + lo;

  // ---- Q fragments, pre-scaled by SCL (so p = exp2(e) directly) ----
  bf16x8 qf[4];
  {
    const unsigned short* qr = qp + (size_t)(b * SEQ + q) * EMBED + h * HDIM + hi * 8;
#pragma unroll
    for (int c = 0; c < 4; ++c) {
      ushort8 u = *(const ushort8*)(qr + 16 * c);
      bf16x8 f;
#pragma unroll
      for (int j = 0; j < 8; ++j) {
        float x = __builtin_bit_cast(float, (unsigned)u[j] << 16) * SCL;
        f[j] = (__bf16)x;
      }
      qf[c] = f;
    }
  }

  // ---- staging: 512 threads; K,V: 16B each; mask: 4B each (256 rows x 8B) ----
  const int srow = tid >> 3;                        // 0..63
  const int srcc = ((tid & 7) * 16) ^ (((tid >> 3) & 7) << 4);  // inv swizzle
  const char* kbase = (const char*)kp
      + ((size_t)(b * SEQ + srow) * EMBED + h * HDIM) * 2 + srcc;
  const char* vbase = (const char*)vpT
      + ((size_t)((b * HEADS + h) * HDIM + srow)) * SEQ * 2 + srcc;
  const char* mgbase = (const char*)mask64
      + ((size_t)(b * SEQ + qc * 256 + (tid >> 1)) * 32) * 8 + (tid & 1) * 4;

  auto STAGE = [&](int buf, int kt) {
    GLD_LDS16(kbase + (size_t)kt * 64 * EMBED * 2, Kb + buf * 8192 + tid * 16);
    GLD_LDS16(vbase + (size_t)kt * 128, Vb + buf * 8192 + tid * 16);
    GLD_LDS4(mgbase + kt * 8, Mb + buf * 2048 + tid * 4);
  };

  f32x16 oacc0, oacc1, oacc2, z16;
#pragma unroll
  for (int i = 0; i < 16; ++i) {
    oacc0[i] = 0.f; oacc1[i] = 0.f; oacc2[i] = 0.f; z16[i] = 0.f;
  }
  bf16x8 ones;
#pragma unroll
  for (int j = 0; j < 8; ++j) ones[j] = (__bf16)1.0f;

  const int swz = (lo & 7) << 4;

  STAGE(0, 0);
  STAGE(1, 1);
  asm volatile("s_waitcnt vmcnt(3)" ::: "memory");   // certify stage 0
  const int NT = SEQ / 64;
  int buf = 0;
  for (int kt = 0; kt < NT; ++kt) {
    __builtin_amdgcn_s_barrier();          // everyone certified buf[kt]
    __builtin_amdgcn_sched_barrier(0);
    if (kt + 2 < NT) {
      int nb = buf + 2; if (nb >= 3) nb -= 3;
      STAGE(nb, kt + 2);
    }
    const unsigned char* Kc = Kb + buf * 8192;
    const unsigned char* Vc = Vb + buf * 8192;
    const unsigned long long mw =
        *(const unsigned long long*)(Mb + buf * 2048 + (wv * 32 + lo) * 8);

    // ---- QK^T (swapped: A=K, B=Q -> D[k][q]) + in-register P build ----
    bf16x8 PA[4];
#pragma unroll
    for (int kg = 0; kg < 2; ++kg) {
      f32x16 e;
      const int krow = kg * 32 + lo;
      __builtin_amdgcn_s_setprio(1);
#pragma unroll
      for (int c = 0; c < 4; ++c) {
        const int colb = (16 * c + 8 * hi) * 2;
        bf16x8 kf = *(const bf16x8*)(Kc + krow * 128 + (colb ^ swz));
        // first MFMA consumes the hoisted zero bank (no per-tile v_movs)
        e = __builtin_amdgcn_mfma_f32_32x32x16_bf16(kf, qf[c],
                                                    c == 0 ? z16 : e, 0, 0, 0);
      }
      __builtin_amdgcn_s_setprio(0);
      // mask + exp: p[4m+j] is k_local = 8m + 4hi + j; bit (8m+j) of mh
      const unsigned mh = (unsigned)(mw >> (kg * 32 + 4 * hi));
      float p[16];
#pragma unroll
      for (int m = 0; m < 4; ++m)
#pragma unroll
        for (int j = 0; j < 4; ++j) {
          float pe = __builtin_amdgcn_exp2f(e[4 * m + j]);
          p[4 * m + j] = (mh & (1u << (8 * m + j))) ? pe : 0.f;
        }
      // pack pairs to bf16; swap lane-halves: one permlane fills 2 words
      unsigned wA0 = cvtpk(p[0], p[1]),   wB0 = cvtpk(p[2], p[3]);
      unsigned wA1 = cvtpk(p[4], p[5]),   wB1 = cvtpk(p[6], p[7]);
      unsigned wA2 = cvtpk(p[8], p[9]),   wB2 = cvtpk(p[10], p[11]);
      unsigned wA3 = cvtpk(p[12], p[13]), wB3 = cvtpk(p[14], p[15]);
      asm("v_permlane32_swap_b32 %0, %1" : "+v"(wA0), "+v"(wA1));
      asm("v_permlane32_swap_b32 %0, %1" : "+v"(wB0), "+v"(wB1));
      asm("v_permlane32_swap_b32 %0, %1" : "+v"(wA2), "+v"(wA3));
      asm("v_permlane32_swap_b32 %0, %1" : "+v"(wB2), "+v"(wB3));
      PA[2 * kg]     = __builtin_bit_cast(bf16x8, (uint4v){wA0, wB0, wA1, wB1});
      PA[2 * kg + 1] = __builtin_bit_cast(bf16x8, (uint4v){wA2, wB2, wA3, wB3});
    }

    // ---- PV: A=P (in reg), B=V^T rows (d) -> D[q][d]; +ones denom ----
    __builtin_amdgcn_s_setprio(1);
#pragma unroll
    for (int c = 0; c < 4; ++c) {
      const int pcolb = 32 * c + 16 * hi;
      bf16x8 pf = PA[c];
      {
        bf16x8 vf = *(const bf16x8*)(Vc + lo * 128 + (pcolb ^ swz));
        oacc0 = __builtin_amdgcn_mfma_f32_32x32x16_bf16(pf, vf, oacc0, 0, 0, 0);
      }
      {
        const int drow = 32 + lo;
        bf16x8 vf = *(const bf16x8*)(Vc + drow * 128 + (pcolb ^ swz));
        oacc1 = __builtin_amdgcn_mfma_f32_32x32x16_bf16(pf, vf, oacc1, 0, 0, 0);
      }
      oacc2 = __builtin_amdgcn_mfma_f32_32x32x16_bf16(pf, ones, oacc2, 0, 0, 0);
    }
    __builtin_amdgcn_s_setprio(0);
    // certify stage kt+1 before next barrier; keep stage kt+2 in flight
    if (kt + 2 < NT) {
      asm volatile("s_waitcnt vmcnt(3)" ::: "memory");
    } else if (kt + 1 < NT) {
      asm volatile("s_waitcnt vmcnt(0)" ::: "memory");
    }
    buf = (buf == 2) ? 0 : buf + 1;
  }

  // ---- oacc2[r] = sum_k P[q_r][k] (same lane layout as oacc0) ----
#pragma unroll
  for (int r = 0; r < 16; ++r) {
    const int qq = qb + (r & 3) + 8 * (r >> 2) + 4 * hi;
    const float dinv = 1.0f / oacc2[r];
    unsigned short* orow = attb + (size_t)(b * SEQ + qq) * EMBED + h * HDIM;
    orow[lo] = f2bf(oacc0[r] * dinv);
    orow[32 + lo] = f2bf(oacc1[r] * dinv);
  }
}

extern "C" void kernel_launch(void* const* d_in, const int* in_sizes, int n_in,
                              void* d_out, int out_size, void* d_ws, size_t ws_size,
                              hipStream_t stream) {
  const float* q    = (const float*)d_in[0];
  const float* k    = (const float*)d_in[1];
  const float* v    = (const float*)d_in[2];
  const int*   mask = (const int*)d_in[3];
  const float* wq_w = (const float*)d_in[4];
  const float* wq_b = (const float*)d_in[5];
  const float* wk_w = (const float*)d_in[6];
  const float* wk_b = (const float*)d_in[7];
  const float* wv_w = (const float*)d_in[8];
  const float* wv_b = (const float*)d_in[9];
  const float* fo_w = (const float*)d_in[10];
  const float* fo_b = (const float*)d_in[11];

  char* ws = (char*)d_ws;
  const size_t MB = 1024 * 1024;
  // base layout (74 MB, verified):
  //   rA @0 (16MB) | weights @16 (8MB) | rB @24 (16MB) | rC @40 (16MB)
  //   rD @56 (16MB) | mask @72 (2MB)
  // extended layout (106 MB) adds rE @74 (16MB), rF @90 (16MB)
  unsigned short* rA  = (unsigned short*)(ws);
  unsigned short* wqb = (unsigned short*)(ws + 16 * MB);
  unsigned short* rB  = (unsigned short*)(ws + 24 * MB);
  unsigned short* rC  = (unsigned short*)(ws + 40 * MB);
  unsigned short* rD  = (unsigned short*)(ws + 56 * MB);
  unsigned long long* m64 = (unsigned long long*)(ws + 72 * MB);
  unsigned short* rE  = (unsigned short*)(ws + 74 * MB);
  unsigned short* rF  = (unsigned short*)(ws + 90 * MB);

  const int NVW = EMBED * EMBED / 8;         // 131072 vec8
  unsigned short* wkb = wqb + (size_t)NVW * 8;
  unsigned short* wvb = wkb + (size_t)NVW * 8;
  unsigned short* fob = wvb + (size_t)NVW * 8;

  // 1. merged prep: pack mask + weights->bf16 + q,k,v->bf16 (one launch)
  prep_kernel<<<PREP_PACK_BLOCKS + PREP_CVT4_BLOCKS + PREP_CVT3_BLOCKS,
                256, 0, stream>>>(
      mask, m64, wq_w, wk_w, wv_w, fo_w, wqb, q, k, v, rA, rB, rC);

  dim3 gg((BATCH * SEQ) / 128, EMBED / 128);

  if (ws_size >= 106 * MB) {
    // 2. all three projections in ONE launch (outputs rD/rE/rF are fresh:
    //    no aliasing with inputs rA/rB/rC within the launch)
    gemm_qkv<<<dim3((BATCH * SEQ) / 128, EMBED / 128, 3), 256, 0, stream>>>(
        rA, rB, rC, wqb, wq_b, wk_b, wv_b, rD, rE, rF);

    // 3. fused masked attention -> bf16 into rA (X_q dead)
    attn7_kernel<<<dim3(8, HEADS, BATCH), 512, 0, stream>>>(rD, rE, rF, m64, rA);

    // 4. output projection -> d_out (f32)
    gemm_bt<2><<<gg, 256, 0, stream>>>(rA, fob, fo_b, (float*)d_out);
  } else {
    // fallback: verified R13 sequential path (74 MB footprint)
    gemm_bt<0><<<gg, 256, 0, stream>>>(rA, wqb, wq_b, rD);   // qp  = rD
    gemm_bt<0><<<gg, 256, 0, stream>>>(rB, wkb, wk_b, rA);   // kp  = rA
    gemm_bt<1><<<gg, 256, 0, stream>>>(rC, wvb, wv_b, rB);   // vpT = rB
    attn7_kernel<<<dim3(8, HEADS, BATCH), 512, 0, stream>>>(rD, rA, rB, m64, rC);
    gemm_bt<2><<<gg, 256, 0, stream>>>(rC, fob, fo_b, (float*)d_out);
  }
}